// Round 2
// baseline (1453.939 us; speedup 1.0000x reference)
//
#include <hip/hip_runtime.h>
#include <hip/hip_bf16.h>
#include <math.h>

#define B_ 4
#define C1 1024
#define C2 256
#define HEADS_ 4
#define DH 64
#define DK 128
#define N_ 2744
#define NT_ 10976
#define EPS_ 1e-5f

__device__ __forceinline__ float bflo(unsigned int u) { return __uint_as_float(u << 16); }
__device__ __forceinline__ float bfhi(unsigned int u) { return __uint_as_float(u & 0xffff0000u); }

// guarded float4 load: zero elements at column >= lim (n is the column of p[0])
__device__ __forceinline__ float4 ldg4(const float* p, int n, int lim) {
    float4 v;
    if (n + 3 < lim) {
        v = *(const float4*)p;
    } else {
        v.x = (n + 0 < lim) ? p[0] : 0.f;
        v.y = (n + 1 < lim) ? p[1] : 0.f;
        v.z = (n + 2 < lim) ? p[2] : 0.f;
        v.w = (n + 3 < lim) ? p[3] : 0.f;
    }
    return v;
}

// ---------------- GEMM: Y[b][o][n] = sum_c W[o][c] * X[b][c][n] (+bias) -------------
// mode 0: plain store to Y0[(b*Cout+o)*N + n]
// mode 1: (Q proj) store to Y0=QA rows d AND Y1=KB rows 64+d  (h=o>>6, d=o&63)
// mode 2: (K proj) store to Y0=KB rows d
__global__ __launch_bounds__(256) void gemm64(
    const float* __restrict__ X, const float* __restrict__ Wm,
    const float* __restrict__ bias, float* __restrict__ Y0, float* __restrict__ Y1,
    int Cin, int Cout, int mode)
{
    __shared__ float As[16][64];  // [k][o]
    __shared__ float Bs[16][64];  // [k][n]
    const int b = blockIdx.z;
    const int otile = blockIdx.y << 6;
    const int ntile = blockIdx.x << 6;
    const int t = threadIdx.x;
    const int ty = t >> 4, tx = t & 15;

    float acc[4][4];
#pragma unroll
    for (int i = 0; i < 4; ++i)
#pragma unroll
        for (int j = 0; j < 4; ++j) acc[i][j] = 0.f;

    const int nk = Cin >> 4;
    for (int kt = 0; kt < nk; ++kt) {
        const int k0 = kt << 4;
        {   // W tile: thread -> o = t>>2, kq = (t&3)*4
            const int o = t >> 2, kq = (t & 3) << 2;
            float4 w = *(const float4*)&Wm[(size_t)(otile + o) * Cin + k0 + kq];
            As[kq + 0][o] = w.x; As[kq + 1][o] = w.y;
            As[kq + 2][o] = w.z; As[kq + 3][o] = w.w;
        }
        {   // X tile: thread -> k = t>>4, nq = (t&15)*4
            const int k = t >> 4, nq = (t & 15) << 2;
            const int n = ntile + nq;
            float4 v = ldg4(&X[((size_t)b * Cin + k0 + k) * N_ + n], n, N_);
            *(float4*)&Bs[k][nq] = v;
        }
        __syncthreads();
#pragma unroll
        for (int k = 0; k < 16; ++k) {
            float4 a = *(const float4*)&As[k][ty << 2];
            float4 bb = *(const float4*)&Bs[k][tx << 2];
            float av[4] = {a.x, a.y, a.z, a.w};
            float bv2[4] = {bb.x, bb.y, bb.z, bb.w};
#pragma unroll
            for (int i = 0; i < 4; ++i)
#pragma unroll
                for (int j = 0; j < 4; ++j)
                    acc[i][j] = fmaf(av[i], bv2[j], acc[i][j]);
        }
        __syncthreads();
    }

#pragma unroll
    for (int i = 0; i < 4; ++i) {
        const int o = otile + (ty << 2) + i;
        const float bvl = bias ? bias[o] : 0.f;
#pragma unroll
        for (int j = 0; j < 4; ++j) {
            const int n = ntile + (tx << 2) + j;
            if (n >= N_) continue;
            const float val = acc[i][j] + bvl;
            if (mode == 0) {
                Y0[((size_t)b * Cout + o) * N_ + n] = val;
            } else {
                const int h = o >> 6, d = o & 63;
                const size_t base = (size_t)(b * HEADS_ + h) * DK;
                if (mode == 1) {
                    Y0[(base + d) * N_ + n] = val;
                    Y1[(base + 64 + d) * N_ + n] = val;
                } else {
                    Y0[(base + d) * N_ + n] = val;
                }
            }
        }
    }
}

// ---------------- BN stats: one block per channel -------------------------------------
__global__ __launch_bounds__(256) void bn_stats(const float* __restrict__ Y,
                                                float* __restrict__ mean, float* __restrict__ istd,
                                                int Cch)
{
    const int ch = blockIdx.x;
    float s = 0.f, s2 = 0.f;
    for (int i = threadIdx.x; i < NT_; i += 256) {
        const int b = i / N_, n = i - b * N_;
        const float v = Y[((size_t)b * Cch + ch) * N_ + n];
        s += v; s2 += v * v;
    }
#pragma unroll
    for (int off = 32; off > 0; off >>= 1) {
        s  += __shfl_down(s, off, 64);
        s2 += __shfl_down(s2, off, 64);
    }
    __shared__ float red[8];
    const int wid = threadIdx.x >> 6;
    if ((threadIdx.x & 63) == 0) { red[wid] = s; red[4 + wid] = s2; }
    __syncthreads();
    if (threadIdx.x == 0) {
        s = red[0] + red[1] + red[2] + red[3];
        s2 = red[4] + red[5] + red[6] + red[7];
        const float m = s / (float)NT_;
        const float var = s2 / (float)NT_ - m * m;
        mean[ch] = m;
        istd[ch] = rsqrtf(var + EPS_);
    }
}

// ---------------- BN apply + ReLU (in place) ------------------------------------------
__global__ __launch_bounds__(256) void bn_apply_relu(float* __restrict__ Y,
    const float* __restrict__ g, const float* __restrict__ bt,
    const float* __restrict__ mean, const float* __restrict__ istd, int Cch)
{
    const int total4 = B_ * Cch * (N_ / 4);
    for (int i4 = blockIdx.x * 256 + threadIdx.x; i4 < total4; i4 += gridDim.x * 256) {
        const int i = i4 << 2;
        const int ch = (i / N_) % Cch;
        const float sc = g[ch] * istd[ch];
        const float sh = bt[ch] - mean[ch] * sc;
        float4 v = *(float4*)&Y[i];
        v.x = fmaxf(fmaf(v.x, sc, sh), 0.f);
        v.y = fmaxf(fmaf(v.y, sc, sh), 0.f);
        v.z = fmaxf(fmaf(v.z, sc, sh), 0.f);
        v.w = fmaxf(fmaf(v.w, sc, sh), 0.f);
        *(float4*)&Y[i] = v;
    }
}

// ---------------- rel = rel_h + rel_w + rel_d into QA rows 64..127 --------------------
__global__ __launch_bounds__(256) void rel_fill(
    const float* __restrict__ rh, const float* __restrict__ rw, const float* __restrict__ rd,
    float* __restrict__ QA)
{
    const int idx = blockIdx.x * 256 + threadIdx.x;
    if (idx >= HEADS_ * DH * N_) return;
    const int n = idx % N_;
    const int hd = idx / N_;           // h*64+d
    const int dd = n % 14;
    const int hh = (n / 14) % 14;
    const int w = n / 196;
    const float v = rh[hd * 196 + hh * 14 + dd]
                  + rw[hd * 196 + w * 14 + dd]
                  + rd[hd * 196 + w * 14 + hh];
    const int h = hd >> 6, d = hd & 63;
#pragma unroll
    for (int b = 0; b < B_; ++b)
        QA[((size_t)(b * HEADS_ + h) * DK + 64 + d) * N_ + n] = v;
}

// ---------------- flash attention, augmented head-dim 128 -----------------------------
// S[n,m] = sum_{dk<128} QA[dk][n] * KB[dk][m];  softmax over m;  O[d,n] = sum_m V[d,m]*P[n,m]
__global__ __launch_bounds__(256) void attn64(
    const float* __restrict__ QA, const float* __restrict__ KB,
    const float* __restrict__ V, float* __restrict__ O)
{
    const int b = blockIdx.z, h = blockIdx.y;
    const int n0 = blockIdx.x << 6;
    const float* qa = QA + (size_t)(b * HEADS_ + h) * DK * N_;
    const float* kb = KB + (size_t)(b * HEADS_ + h) * DK * N_;
    const float* vp = V + ((size_t)b * C2 + h * DH) * N_;
    float*       op = O + ((size_t)b * C2 + h * DH) * N_;

    __shared__ __hip_bfloat16 As[DK][64];   // 16 KB  [dk][n]
    __shared__ __hip_bfloat16 Bs[DK][64];   // 16 KB  [dk][m]; lower half reused as Vs[m][d]
    __shared__ float Ps[64][68];            // 17 KB  [m][n] (padded)
    __shared__ float rowscale[64];
    __shared__ float rowl[64];

    const int t = threadIdx.x;
    const int ty = t >> 4, tx = t & 15;

    {   // stage As = [Q;REL] cols n0..n0+63
        const int n = n0 + (tx << 2);
#pragma unroll
        for (int s = 0; s < 8; ++s) {
            const int dk = ty + (s << 4);
            float4 v4 = ldg4(&qa[(size_t)dk * N_ + n], n, N_);
            __hip_bfloat16* dst = &As[dk][tx << 2];
            dst[0] = __float2bfloat16(v4.x);
            dst[1] = __float2bfloat16(v4.y);
            dst[2] = __float2bfloat16(v4.z);
            dst[3] = __float2bfloat16(v4.w);
        }
    }

    float m_r[4], l_r[4], acc[4][4];
#pragma unroll
    for (int i = 0; i < 4; ++i) {
        m_r[i] = -INFINITY; l_r[i] = 0.f;
#pragma unroll
        for (int j = 0; j < 4; ++j) acc[i][j] = 0.f;
    }

    const int nch = (N_ + 63) >> 6;  // 43
    for (int c = 0; c < nch; ++c) {
        const int m0 = c << 6;
        __syncthreads();   // protect Bs/Ps/rowscale from previous iteration readers
        {   // stage Bs = [K;Q] cols m0..m0+63
            const int m = m0 + (tx << 2);
#pragma unroll
            for (int s = 0; s < 8; ++s) {
                const int dk = ty + (s << 4);
                float4 v4 = ldg4(&kb[(size_t)dk * N_ + m], m, N_);
                __hip_bfloat16* dst = &Bs[dk][tx << 2];
                dst[0] = __float2bfloat16(v4.x);
                dst[1] = __float2bfloat16(v4.y);
                dst[2] = __float2bfloat16(v4.z);
                dst[3] = __float2bfloat16(v4.w);
            }
        }
        __syncthreads();
        // ---- S tile: rows n = ty*4+i, cols m = tx*4+j
        float sv[4][4];
#pragma unroll
        for (int i = 0; i < 4; ++i)
#pragma unroll
            for (int j = 0; j < 4; ++j) sv[i][j] = 0.f;
#pragma unroll 4
        for (int dk = 0; dk < DK; ++dk) {
            const uint2 au = *(const uint2*)&As[dk][ty << 2];
            const uint2 bu = *(const uint2*)&Bs[dk][tx << 2];
            const float av[4] = {bflo(au.x), bfhi(au.x), bflo(au.y), bfhi(au.y)};
            const float bv2[4] = {bflo(bu.x), bfhi(bu.x), bflo(bu.y), bfhi(bu.y)};
#pragma unroll
            for (int i = 0; i < 4; ++i)
#pragma unroll
                for (int j = 0; j < 4; ++j)
                    sv[i][j] = fmaf(av[i], bv2[j], sv[i][j]);
        }
#pragma unroll
        for (int j = 0; j < 4; ++j) {
            if (m0 + (tx << 2) + j >= N_) {
                sv[0][j] = -1e30f; sv[1][j] = -1e30f; sv[2][j] = -1e30f; sv[3][j] = -1e30f;
            }
        }
        // ---- online softmax per row (16 lanes with same ty share a row group)
#pragma unroll
        for (int i = 0; i < 4; ++i) {
            float rmax = fmaxf(fmaxf(sv[i][0], sv[i][1]), fmaxf(sv[i][2], sv[i][3]));
#pragma unroll
            for (int mk = 1; mk < 16; mk <<= 1) rmax = fmaxf(rmax, __shfl_xor(rmax, mk, 64));
            const float mnew = fmaxf(m_r[i], rmax);
            float p[4], psum = 0.f;
#pragma unroll
            for (int j = 0; j < 4; ++j) { p[j] = __expf(sv[i][j] - mnew); psum += p[j]; }
#pragma unroll
            for (int mk = 1; mk < 16; mk <<= 1) psum += __shfl_xor(psum, mk, 64);
            const float scl = __expf(m_r[i] - mnew);
            l_r[i] = l_r[i] * scl + psum;
            m_r[i] = mnew;
#pragma unroll
            for (int j = 0; j < 4; ++j) Ps[(tx << 2) + j][(ty << 2) + i] = p[j];
            if (tx == 0) rowscale[(ty << 2) + i] = scl;
        }
        __syncthreads();   // Ps/rowscale ready; S reads of Bs done
        {   // stage V chunk transposed into Bs region: Vs[m][d] bf16
            __hip_bfloat16* Vs = &Bs[0][0];
            const int d = t >> 2, qq = t & 3;
#pragma unroll
            for (int s = 0; s < 4; ++s) {
                const int m = (qq << 4) + (s << 2);
                const int gm = m0 + m;
                float4 v4 = ldg4(&vp[(size_t)d * N_ + gm], gm, N_);
                Vs[(m + 0) * 64 + d] = __float2bfloat16(v4.x);
                Vs[(m + 1) * 64 + d] = __float2bfloat16(v4.y);
                Vs[(m + 2) * 64 + d] = __float2bfloat16(v4.z);
                Vs[(m + 3) * 64 + d] = __float2bfloat16(v4.w);
            }
        }
        __syncthreads();
        // ---- rescale + PV: thread -> d = ty*4+i, n = tx*4+j
#pragma unroll
        for (int j = 0; j < 4; ++j) {
            const float rs = rowscale[(tx << 2) + j];
#pragma unroll
            for (int i = 0; i < 4; ++i) acc[i][j] *= rs;
        }
        const __hip_bfloat16* Vs = &Bs[0][0];
#pragma unroll 4
        for (int mm = 0; mm < 64; ++mm) {
            const uint2 vu = *(const uint2*)&Vs[mm * 64 + (ty << 2)];
            const float vv[4] = {bflo(vu.x), bfhi(vu.x), bflo(vu.y), bfhi(vu.y)};
            const float4 p4 = *(const float4*)&Ps[mm][tx << 2];
            const float pv[4] = {p4.x, p4.y, p4.z, p4.w};
#pragma unroll
            for (int i = 0; i < 4; ++i)
#pragma unroll
                for (int j = 0; j < 4; ++j)
                    acc[i][j] = fmaf(vv[i], pv[j], acc[i][j]);
        }
    }
    if (tx == 0) {
#pragma unroll
        for (int i = 0; i < 4; ++i) rowl[(ty << 2) + i] = l_r[i];
    }
    __syncthreads();
#pragma unroll
    for (int j = 0; j < 4; ++j) {
        const int n = n0 + (tx << 2) + j;
        if (n >= N_) continue;
        const float inv = 1.f / rowl[(tx << 2) + j];
#pragma unroll
        for (int i = 0; i < 4; ++i)
            op[(size_t)((ty << 2) + i) * N_ + n] = acc[i][j] * inv;
    }
}

// ---------------- final: out = relu(bn3(out) + x), in place ---------------------------
__global__ __launch_bounds__(256) void bn_add_relu(float* __restrict__ Y, const float* __restrict__ X,
    const float* __restrict__ g, const float* __restrict__ bt,
    const float* __restrict__ mean, const float* __restrict__ istd)
{
    const int total4 = B_ * C1 * (N_ / 4);
    for (int i4 = blockIdx.x * 256 + threadIdx.x; i4 < total4; i4 += gridDim.x * 256) {
        const int i = i4 << 2;
        const int ch = (i / N_) % C1;
        const float sc = g[ch] * istd[ch];
        const float sh = bt[ch] - mean[ch] * sc;
        float4 y = *(float4*)&Y[i];
        const float4 x = *(const float4*)&X[i];
        y.x = fmaxf(fmaf(y.x, sc, sh) + x.x, 0.f);
        y.y = fmaxf(fmaf(y.y, sc, sh) + x.y, 0.f);
        y.z = fmaxf(fmaf(y.z, sc, sh) + x.z, 0.f);
        y.w = fmaxf(fmaf(y.w, sc, sh) + x.w, 0.f);
        *(float4*)&Y[i] = y;
    }
}

extern "C" void kernel_launch(void* const* d_in, const int* in_sizes, int n_in,
                              void* d_out, int out_size, void* d_ws, size_t ws_size,
                              hipStream_t stream)
{
    const float* x  = (const float*)d_in[0];
    const float* W1 = (const float*)d_in[1];
    const float* g1 = (const float*)d_in[2];
    const float* b1 = (const float*)d_in[3];
    const float* Wq = (const float*)d_in[4];
    const float* bq = (const float*)d_in[5];
    const float* Wk = (const float*)d_in[6];
    const float* bk = (const float*)d_in[7];
    const float* Wv = (const float*)d_in[8];
    const float* bv = (const float*)d_in[9];
    const float* rh = (const float*)d_in[10];
    const float* rw = (const float*)d_in[11];
    const float* rd = (const float*)d_in[12];
    const float* g2 = (const float*)d_in[13];
    const float* b2 = (const float*)d_in[14];
    const float* W3 = (const float*)d_in[15];
    const float* g3 = (const float*)d_in[16];
    const float* b3 = (const float*)d_in[17];
    float* out = (float*)d_out;

    float* ws = (float*)d_ws;
    const size_t SZ_BCN = (size_t)B_ * C2 * N_;          // 2,809,856
    const size_t SZ_QA  = (size_t)B_ * HEADS_ * DK * N_; // 5,619,712
    float* Y1 = ws;
    float* Vb = Y1 + SZ_BCN;
    float* Ob = Vb + SZ_BCN;
    float* QA = Ob + SZ_BCN;
    float* KB = QA + SZ_QA;
    float* st = KB + SZ_QA;
    float* m1 = st;        float* i1 = st + 256;
    float* m2 = st + 512;  float* i2 = st + 768;
    float* m3 = st + 1024; float* i3 = st + 2048;

    dim3 blk(256);
    const int NTILES = (N_ + 63) / 64;  // 43

    // conv1 -> Y1 ; BN1 ; ReLU
    gemm64<<<dim3(NTILES, C2 / 64, B_), blk, 0, stream>>>(x, W1, nullptr, Y1, nullptr, C1, C2, 0);
    bn_stats<<<dim3(C2), blk, 0, stream>>>(Y1, m1, i1, C2);
    bn_apply_relu<<<dim3(1024), blk, 0, stream>>>(Y1, g1, b1, m1, i1, C2);

    // Q/K/V projections into augmented buffers
    gemm64<<<dim3(NTILES, C2 / 64, B_), blk, 0, stream>>>(Y1, Wq, bq, QA, KB, C2, C2, 1);
    gemm64<<<dim3(NTILES, C2 / 64, B_), blk, 0, stream>>>(Y1, Wk, bk, KB, nullptr, C2, C2, 2);
    gemm64<<<dim3(NTILES, C2 / 64, B_), blk, 0, stream>>>(Y1, Wv, bv, Vb, nullptr, C2, C2, 0);
    rel_fill<<<dim3((HEADS_ * DH * N_ + 255) / 256), blk, 0, stream>>>(rh, rw, rd, QA);

    // flash attention
    attn64<<<dim3(NTILES, HEADS_, B_), blk, 0, stream>>>(QA, KB, Vb, Ob);

    // BN2 ; ReLU
    bn_stats<<<dim3(C2), blk, 0, stream>>>(Ob, m2, i2, C2);
    bn_apply_relu<<<dim3(1024), blk, 0, stream>>>(Ob, g2, b2, m2, i2, C2);

    // conv3 -> out ; BN3 ; add residual ; ReLU
    gemm64<<<dim3(NTILES, C1 / 64, B_), blk, 0, stream>>>(Ob, W3, nullptr, out, nullptr, C2, C1, 0);
    bn_stats<<<dim3(C1), blk, 0, stream>>>(out, m3, i3, C1);
    bn_add_relu<<<dim3(2048), blk, 0, stream>>>(out, x, g3, b3, m3, i3);

    (void)in_sizes; (void)n_in; (void)out_size; (void)ws_size;
}

// Round 3
// 646.343 us; speedup vs baseline: 2.2495x; 2.2495x over previous
//
#include <hip/hip_runtime.h>
#include <hip/hip_bf16.h>
#include <math.h>

#define B_ 4
#define C1 1024
#define C2 256
#define HEADS_ 4
#define DH 64
#define DK 128
#define N_ 2744
#define NT_ 10976
#define EPS_ 1e-5f
#define QB 128
#define KBT 64
#define NKT 43      // ceil(2744/64)
#define NQT 22      // ceil(2744/128)

typedef float f32x4 __attribute__((ext_vector_type(4)));
typedef short bf16x8 __attribute__((ext_vector_type(8)));
typedef unsigned short us4 __attribute__((ext_vector_type(4)));

static __device__ __forceinline__ unsigned short bfbits(float x) {
    __hip_bfloat16 t = __float2bfloat16(x);
    unsigned short u;
    __builtin_memcpy(&u, &t, 2);
    return u;
}

// guarded float4 load: zero elements at column >= lim (n is the column of p[0])
__device__ __forceinline__ float4 ldg4(const float* p, int n, int lim) {
    float4 v;
    if (n + 3 < lim) {
        v = *(const float4*)p;
    } else {
        v.x = (n + 0 < lim) ? p[0] : 0.f;
        v.y = (n + 1 < lim) ? p[1] : 0.f;
        v.z = (n + 2 < lim) ? p[2] : 0.f;
        v.w = (n + 3 < lim) ? p[3] : 0.f;
    }
    return v;
}

// ---------------- GEMM: Y[b][o][n] = sum_c W[o][c] * X[b][c][n] (+bias) -------------
// mode 0: f32 store to Y0[(b*Cout+o)*N + n]
// mode 1: (Q proj) bf16 transposed: QAt[(bh*N+n)*128 + d]  AND  KBt[(bh*N+n)*128 + 64+d]
// mode 2: (K proj) bf16 transposed: KBt[(bh*N+n)*128 + d]
// mode 3: (V proj) bf16 store to Y0b16[(b*Cout+o)*N + n]
__global__ __launch_bounds__(256) void gemm64(
    const float* __restrict__ X, const float* __restrict__ Wm,
    const float* __restrict__ bias, void* __restrict__ Y0, void* __restrict__ Y1,
    int Cin, int Cout, int mode)
{
    __shared__ float As[16][64];  // [k][o]
    __shared__ float Bs[16][64];  // [k][n]
    const int b = blockIdx.z;
    const int otile = blockIdx.y << 6;
    const int ntile = blockIdx.x << 6;
    const int t = threadIdx.x;
    const int ty = t >> 4, tx = t & 15;

    float acc[4][4];
#pragma unroll
    for (int i = 0; i < 4; ++i)
#pragma unroll
        for (int j = 0; j < 4; ++j) acc[i][j] = 0.f;

    const int nk = Cin >> 4;
    for (int kt = 0; kt < nk; ++kt) {
        const int k0 = kt << 4;
        {   // W tile
            const int o = t >> 2, kq = (t & 3) << 2;
            float4 w = *(const float4*)&Wm[(size_t)(otile + o) * Cin + k0 + kq];
            As[kq + 0][o] = w.x; As[kq + 1][o] = w.y;
            As[kq + 2][o] = w.z; As[kq + 3][o] = w.w;
        }
        {   // X tile
            const int k = t >> 4, nq = (t & 15) << 2;
            const int n = ntile + nq;
            float4 v = ldg4(&X[((size_t)b * Cin + k0 + k) * N_ + n], n, N_);
            *(float4*)&Bs[k][nq] = v;
        }
        __syncthreads();
#pragma unroll
        for (int k = 0; k < 16; ++k) {
            float4 a = *(const float4*)&As[k][ty << 2];
            float4 bb = *(const float4*)&Bs[k][tx << 2];
            float av[4] = {a.x, a.y, a.z, a.w};
            float bv2[4] = {bb.x, bb.y, bb.z, bb.w};
#pragma unroll
            for (int i = 0; i < 4; ++i)
#pragma unroll
                for (int j = 0; j < 4; ++j)
                    acc[i][j] = fmaf(av[i], bv2[j], acc[i][j]);
        }
        __syncthreads();
    }

    float bvl[4];
#pragma unroll
    for (int i = 0; i < 4; ++i)
        bvl[i] = bias ? bias[otile + (ty << 2) + i] : 0.f;

    if (mode == 0) {
        float* y = (float*)Y0;
#pragma unroll
        for (int i = 0; i < 4; ++i) {
            const int o = otile + (ty << 2) + i;
#pragma unroll
            for (int j = 0; j < 4; ++j) {
                const int n = ntile + (tx << 2) + j;
                if (n < N_) y[((size_t)b * Cout + o) * N_ + n] = acc[i][j] + bvl[i];
            }
        }
    } else if (mode == 3) {
        unsigned short* y = (unsigned short*)Y0;
#pragma unroll
        for (int i = 0; i < 4; ++i) {
            const int o = otile + (ty << 2) + i;
            const int nq = ntile + (tx << 2);
            us4 pk;
#pragma unroll
            for (int j = 0; j < 4; ++j) pk[j] = bfbits(acc[i][j] + bvl[i]);
            if (nq + 3 < N_) {
                *(us4*)&y[((size_t)b * Cout + o) * N_ + nq] = pk;
            } else {
#pragma unroll
                for (int j = 0; j < 4; ++j)
                    if (nq + j < N_) y[((size_t)b * Cout + o) * N_ + nq + j] = pk[j];
            }
        }
    } else {
        // mode 1/2: transposed bf16; Cout==256, h = otile>>6, d = ty*4+i (0..63)
        const int h = otile >> 6;
        const int bh = b * HEADS_ + h;
        const int d0 = ty << 2;
        unsigned short* yq = (unsigned short*)Y0;
        unsigned short* yk = (unsigned short*)Y1;
#pragma unroll
        for (int j = 0; j < 4; ++j) {
            const int n = ntile + (tx << 2) + j;
            if (n >= N_) continue;
            us4 pk;
#pragma unroll
            for (int i = 0; i < 4; ++i) pk[i] = bfbits(acc[i][j] + bvl[i]);
            const size_t rowb = ((size_t)bh * N_ + n) * 128;
            if (mode == 1) {
                *(us4*)&yq[rowb + d0] = pk;
                *(us4*)&yk[rowb + 64 + d0] = pk;
            } else {
                *(us4*)&yq[rowb + d0] = pk;
            }
        }
    }
}

// ---------------- BN stats: one block per channel -------------------------------------
__global__ __launch_bounds__(256) void bn_stats(const float* __restrict__ Y,
                                                float* __restrict__ mean, float* __restrict__ istd,
                                                int Cch)
{
    const int ch = blockIdx.x;
    float s = 0.f, s2 = 0.f;
    for (int i = threadIdx.x; i < NT_; i += 256) {
        const int b = i / N_, n = i - b * N_;
        const float v = Y[((size_t)b * Cch + ch) * N_ + n];
        s += v; s2 += v * v;
    }
#pragma unroll
    for (int off = 32; off > 0; off >>= 1) {
        s  += __shfl_down(s, off, 64);
        s2 += __shfl_down(s2, off, 64);
    }
    __shared__ float red[8];
    const int wid = threadIdx.x >> 6;
    if ((threadIdx.x & 63) == 0) { red[wid] = s; red[4 + wid] = s2; }
    __syncthreads();
    if (threadIdx.x == 0) {
        s = red[0] + red[1] + red[2] + red[3];
        s2 = red[4] + red[5] + red[6] + red[7];
        const float m = s / (float)NT_;
        const float var = s2 / (float)NT_ - m * m;
        mean[ch] = m;
        istd[ch] = rsqrtf(var + EPS_);
    }
}

// ---------------- BN apply + ReLU (in place) ------------------------------------------
__global__ __launch_bounds__(256) void bn_apply_relu(float* __restrict__ Y,
    const float* __restrict__ g, const float* __restrict__ bt,
    const float* __restrict__ mean, const float* __restrict__ istd, int Cch)
{
    const int total4 = B_ * Cch * (N_ / 4);
    for (int i4 = blockIdx.x * 256 + threadIdx.x; i4 < total4; i4 += gridDim.x * 256) {
        const int i = i4 << 2;
        const int ch = (i / N_) % Cch;
        const float sc = g[ch] * istd[ch];
        const float sh = bt[ch] - mean[ch] * sc;
        float4 v = *(float4*)&Y[i];
        v.x = fmaxf(fmaf(v.x, sc, sh), 0.f);
        v.y = fmaxf(fmaf(v.y, sc, sh), 0.f);
        v.z = fmaxf(fmaf(v.z, sc, sh), 0.f);
        v.w = fmaxf(fmaf(v.w, sc, sh), 0.f);
        *(float4*)&Y[i] = v;
    }
}

// ---------------- rel = rel_h + rel_w + rel_d into QAt cols 64..127 (bf16) ------------
__global__ __launch_bounds__(256) void rel_fill(
    const float* __restrict__ rh, const float* __restrict__ rw, const float* __restrict__ rd,
    unsigned short* __restrict__ QAt)
{
    const int idx = blockIdx.x * 256 + threadIdx.x;  // (h*16+dq)*N_ + n
    if (idx >= HEADS_ * 16 * N_) return;
    const int n = idx % N_;
    const int t2 = idx / N_;
    const int h = t2 >> 4, dq = t2 & 15;
    const int dd = n % 14;
    const int hh = (n / 14) % 14;
    const int w = n / 196;
    us4 pk;
#pragma unroll
    for (int i = 0; i < 4; ++i) {
        const int base = (h * 64 + dq * 4 + i) * 196;
        const float v = rh[base + hh * 14 + dd]
                      + rw[base + w * 14 + dd]
                      + rd[base + w * 14 + hh];
        pk[i] = bfbits(v);
    }
#pragma unroll
    for (int b = 0; b < B_; ++b)
        *(us4*)&QAt[((size_t)(b * HEADS_ + h) * N_ + n) * 128 + 64 + dq * 4] = pk;
}

// ---------------- MFMA flash attention, augmented head-dim 128 ------------------------
// S[n,m] = QAt_row(n) . KBt_row(m); softmax over m; O[d,n] = sum_m V[d,m] P[n,m]
#define LQS 0
#define LKS 32768
#define LVS 49152
#define LPS 57344
#define LDS_TOT 73728

__global__ __launch_bounds__(256, 2) void attn_mfma(
    const unsigned short* __restrict__ QAt, const unsigned short* __restrict__ KBt,
    const unsigned short* __restrict__ Vb, float* __restrict__ O)
{
    __shared__ char smem[LDS_TOT];
    const int bid = blockIdx.x;                    // 352 = 8 XCD chunks of 44 (= 2 bh)
    const int sw = (bid & 7) * 44 + (bid >> 3);
    const int bh = sw / NQT;
    const int ntile = sw - bh * NQT;
    const int n0 = ntile << 7;
    const int b = bh >> 2, h = bh & 3;

    const unsigned short* qat = QAt + (size_t)bh * N_ * 128;
    const unsigned short* kbt = KBt + (size_t)bh * N_ * 128;
    const unsigned short* vb  = Vb + (size_t)(b * C2 + h * DH) * N_;
    float* op = O + (size_t)(b * C2 + h * DH) * N_;

    const int t = threadIdx.x;
    const int wave = t >> 6, lane = t & 63;
    const int l4 = lane >> 4, l15 = lane & 15;
    const int wq0 = wave << 5;

    // ---- stage Q tile [128 q][128 dk] bf16, XOR-swizzled
#pragma unroll
    for (int c = 0; c < 8; ++c) {
        const int o = (wave * 8 + c) * 1024 + lane * 16;
        const int q = o >> 8, cb = o & 255;
        const int gq = min(n0 + q, N_ - 1);
        const bf16x8 v = *(const bf16x8*)(qat + (size_t)gq * 128 + (cb >> 1));
        *(bf16x8*)&smem[LQS + q * 256 + (cb ^ ((q & 7) << 4))] = v;
    }

    float m_r[2][4], l_r[2][4];
    f32x4 oacc[2][4];
#pragma unroll
    for (int mi = 0; mi < 2; ++mi)
#pragma unroll
        for (int j = 0; j < 4; ++j) { m_r[mi][j] = -1e30f; l_r[mi][j] = 0.f; }
#pragma unroll
    for (int mi = 0; mi < 2; ++mi)
#pragma unroll
        for (int ds = 0; ds < 4; ++ds) oacc[mi][ds] = (f32x4){0.f, 0.f, 0.f, 0.f};

    for (int kt = 0; kt < NKT; ++kt) {
        const int m0 = kt << 6;
        // ---- stage K tile [64 m][128 dk]
#pragma unroll
        for (int c = 0; c < 4; ++c) {
            const int o = (wave * 4 + c) * 1024 + lane * 16;
            const int r = o >> 8, cb = o & 255;
            const int gm = min(m0 + r, N_ - 1);
            const bf16x8 v = *(const bf16x8*)(kbt + (size_t)gm * 128 + (cb >> 1));
            *(bf16x8*)&smem[LKS + r * 256 + (cb ^ ((r & 7) << 4))] = v;
        }
        // ---- stage V tile [64 d][64 m]
#pragma unroll
        for (int c = 0; c < 2; ++c) {
            const int o = (wave * 2 + c) * 1024 + lane * 16;
            const int d = o >> 7, cb = o & 127;
            const int ms = min(m0 + (cb >> 1), N_ - 8);
            const bf16x8 v = *(const bf16x8*)(vb + (size_t)d * N_ + ms);
            *(bf16x8*)&smem[LVS + d * 128 + (cb ^ ((d & 7) << 4))] = v;
        }
        __syncthreads();

        // ---- QK^T: wave tile 32 q x 64 m, K=128
        f32x4 s[2][4];
#pragma unroll
        for (int mi = 0; mi < 2; ++mi)
#pragma unroll
            for (int ks = 0; ks < 4; ++ks) s[mi][ks] = (f32x4){0.f, 0.f, 0.f, 0.f};
#pragma unroll
        for (int kc = 0; kc < 4; ++kc) {
            const int colb = kc * 64 + l4 * 16;
            const int q0r = wq0 + l15;
            const int q1r = wq0 + 16 + l15;
            const bf16x8 a0 = *(const bf16x8*)&smem[LQS + q0r * 256 + (colb ^ ((q0r & 7) << 4))];
            const bf16x8 a1 = *(const bf16x8*)&smem[LQS + q1r * 256 + (colb ^ ((q1r & 7) << 4))];
#pragma unroll
            for (int ks = 0; ks < 4; ++ks) {
                const int r = ks * 16 + l15;
                const bf16x8 bf = *(const bf16x8*)&smem[LKS + r * 256 + (colb ^ ((r & 7) << 4))];
                s[0][ks] = __builtin_amdgcn_mfma_f32_16x16x32_bf16(a0, bf, s[0][ks], 0, 0, 0);
                s[1][ks] = __builtin_amdgcn_mfma_f32_16x16x32_bf16(a1, bf, s[1][ks], 0, 0, 0);
            }
        }
        if (m0 + KBT > N_) {
#pragma unroll
            for (int ks = 0; ks < 4; ++ks)
                if (m0 + ks * 16 + l15 >= N_) {
                    s[0][ks] = (f32x4){-1e30f, -1e30f, -1e30f, -1e30f};
                    s[1][ks] = (f32x4){-1e30f, -1e30f, -1e30f, -1e30f};
                }
        }

        // ---- online softmax (rows live in-lane: row = l4*4+j per 16-lane group)
        const int pbase = LPS + (wave << 12);
#pragma unroll
        for (int mi = 0; mi < 2; ++mi) {
#pragma unroll
            for (int j = 0; j < 4; ++j) {
                const float v0 = s[mi][0][j], v1 = s[mi][1][j];
                const float v2 = s[mi][2][j], v3 = s[mi][3][j];
                float rmax = fmaxf(fmaxf(v0, v1), fmaxf(v2, v3));
                rmax = fmaxf(rmax, __shfl_xor(rmax, 1, 64));
                rmax = fmaxf(rmax, __shfl_xor(rmax, 2, 64));
                rmax = fmaxf(rmax, __shfl_xor(rmax, 4, 64));
                rmax = fmaxf(rmax, __shfl_xor(rmax, 8, 64));
                const float mnew = fmaxf(m_r[mi][j], rmax);
                const float p0 = __expf(v0 - mnew), p1 = __expf(v1 - mnew);
                const float p2 = __expf(v2 - mnew), p3 = __expf(v3 - mnew);
                float ps = p0 + p1 + p2 + p3;
                ps += __shfl_xor(ps, 1, 64);
                ps += __shfl_xor(ps, 2, 64);
                ps += __shfl_xor(ps, 4, 64);
                ps += __shfl_xor(ps, 8, 64);
                const float scl = __expf(m_r[mi][j] - mnew);
                m_r[mi][j] = mnew;
                l_r[mi][j] = l_r[mi][j] * scl + ps;
                oacc[mi][0][j] *= scl; oacc[mi][1][j] *= scl;
                oacc[mi][2][j] *= scl; oacc[mi][3][j] *= scl;
                const int r = mi * 16 + l4 * 4 + j;
                const int rb = pbase + r * 128, sz = (r & 7) << 4;
                *(unsigned short*)&smem[rb + ((l15 * 2 +  0) ^ sz)] = bfbits(p0);
                *(unsigned short*)&smem[rb + ((l15 * 2 + 32) ^ sz)] = bfbits(p1);
                *(unsigned short*)&smem[rb + ((l15 * 2 + 64) ^ sz)] = bfbits(p2);
                *(unsigned short*)&smem[rb + ((l15 * 2 + 96) ^ sz)] = bfbits(p3);
            }
        }

        // ---- PV: O[32 q][64 d] += P[32 q][64 m] * V (B-frag from Vs[d][m])
#pragma unroll
        for (int mc = 0; mc < 2; ++mc) {
            const int colb = mc * 64 + l4 * 16;
            const int r0 = l15, r1 = 16 + l15;
            const bf16x8 pa0 = *(const bf16x8*)&smem[pbase + r0 * 128 + (colb ^ ((r0 & 7) << 4))];
            const bf16x8 pa1 = *(const bf16x8*)&smem[pbase + r1 * 128 + (colb ^ ((r1 & 7) << 4))];
#pragma unroll
            for (int ds = 0; ds < 4; ++ds) {
                const int d = ds * 16 + l15;
                const bf16x8 bv = *(const bf16x8*)&smem[LVS + d * 128 + (colb ^ ((d & 7) << 4))];
                oacc[0][ds] = __builtin_amdgcn_mfma_f32_16x16x32_bf16(pa0, bv, oacc[0][ds], 0, 0, 0);
                oacc[1][ds] = __builtin_amdgcn_mfma_f32_16x16x32_bf16(pa1, bv, oacc[1][ds], 0, 0, 0);
            }
        }
        __syncthreads();
    }

    // ---- epilogue: O / l
#pragma unroll
    for (int mi = 0; mi < 2; ++mi) {
#pragma unroll
        for (int j = 0; j < 4; ++j) {
            const float inv = 1.f / l_r[mi][j];
            const int n = n0 + wq0 + mi * 16 + l4 * 4 + j;
            if (n < N_) {
#pragma unroll
                for (int ds = 0; ds < 4; ++ds)
                    op[(size_t)(ds * 16 + l15) * N_ + n] = oacc[mi][ds][j] * inv;
            }
        }
    }
}

// ---------------- final: out = relu(bn3(out) + x), in place ---------------------------
__global__ __launch_bounds__(256) void bn_add_relu(float* __restrict__ Y, const float* __restrict__ X,
    const float* __restrict__ g, const float* __restrict__ bt,
    const float* __restrict__ mean, const float* __restrict__ istd)
{
    const int total4 = B_ * C1 * (N_ / 4);
    for (int i4 = blockIdx.x * 256 + threadIdx.x; i4 < total4; i4 += gridDim.x * 256) {
        const int i = i4 << 2;
        const int ch = (i / N_) % C1;
        const float sc = g[ch] * istd[ch];
        const float sh = bt[ch] - mean[ch] * sc;
        float4 y = *(float4*)&Y[i];
        const float4 x = *(const float4*)&X[i];
        y.x = fmaxf(fmaf(y.x, sc, sh) + x.x, 0.f);
        y.y = fmaxf(fmaf(y.y, sc, sh) + x.y, 0.f);
        y.z = fmaxf(fmaf(y.z, sc, sh) + x.z, 0.f);
        y.w = fmaxf(fmaf(y.w, sc, sh) + x.w, 0.f);
        *(float4*)&Y[i] = y;
    }
}

extern "C" void kernel_launch(void* const* d_in, const int* in_sizes, int n_in,
                              void* d_out, int out_size, void* d_ws, size_t ws_size,
                              hipStream_t stream)
{
    const float* x  = (const float*)d_in[0];
    const float* W1 = (const float*)d_in[1];
    const float* g1 = (const float*)d_in[2];
    const float* b1 = (const float*)d_in[3];
    const float* Wq = (const float*)d_in[4];
    const float* bq = (const float*)d_in[5];
    const float* Wk = (const float*)d_in[6];
    const float* bk = (const float*)d_in[7];
    const float* Wv = (const float*)d_in[8];
    const float* bv = (const float*)d_in[9];
    const float* rh = (const float*)d_in[10];
    const float* rw = (const float*)d_in[11];
    const float* rd = (const float*)d_in[12];
    const float* g2 = (const float*)d_in[13];
    const float* b2 = (const float*)d_in[14];
    const float* W3 = (const float*)d_in[15];
    const float* g3 = (const float*)d_in[16];
    const float* b3 = (const float*)d_in[17];
    float* out = (float*)d_out;

    float* ws = (float*)d_ws;
    const size_t SZ_BCN = (size_t)B_ * C2 * N_;            // 2,809,856 floats
    float* Y1  = ws;                                        // f32 [b][256][N]
    float* Ob  = Y1 + SZ_BCN;                               // f32 [b][256][N]
    unsigned short* QAt = (unsigned short*)(Ob + SZ_BCN);   // bf16 [bh][N][128]
    unsigned short* KBt = (unsigned short*)(QAt + 2 * SZ_BCN); // bf16 [bh][N][128]
    unsigned short* Vb16 = (unsigned short*)(KBt + 2 * SZ_BCN); // bf16 [b][256][N]
    float* st = (float*)(Vb16 + 2 * SZ_BCN);
    float* m1 = st;        float* i1 = st + 256;
    float* m2 = st + 512;  float* i2 = st + 768;
    float* m3 = st + 1024; float* i3 = st + 2048;

    dim3 blk(256);
    const int NTILES = (N_ + 63) / 64;  // 43

    // conv1 -> Y1 ; BN1 ; ReLU
    gemm64<<<dim3(NTILES, C2 / 64, B_), blk, 0, stream>>>(x, W1, nullptr, Y1, nullptr, C1, C2, 0);
    bn_stats<<<dim3(C2), blk, 0, stream>>>(Y1, m1, i1, C2);
    bn_apply_relu<<<dim3(1024), blk, 0, stream>>>(Y1, g1, b1, m1, i1, C2);

    // Q/K/V projections into bf16 attention layouts
    gemm64<<<dim3(NTILES, C2 / 64, B_), blk, 0, stream>>>(Y1, Wq, bq, QAt, KBt, C2, C2, 1);
    gemm64<<<dim3(NTILES, C2 / 64, B_), blk, 0, stream>>>(Y1, Wk, bk, KBt, nullptr, C2, C2, 2);
    gemm64<<<dim3(NTILES, C2 / 64, B_), blk, 0, stream>>>(Y1, Wv, bv, Vb16, nullptr, C2, C2, 3);
    rel_fill<<<dim3((HEADS_ * 16 * N_ + 255) / 256), blk, 0, stream>>>(rh, rw, rd, QAt);

    // MFMA flash attention
    attn_mfma<<<dim3(NQT * 16), blk, 0, stream>>>(QAt, KBt, Vb16, Ob);

    // BN2 ; ReLU
    bn_stats<<<dim3(C2), blk, 0, stream>>>(Ob, m2, i2, C2);
    bn_apply_relu<<<dim3(1024), blk, 0, stream>>>(Ob, g2, b2, m2, i2, C2);

    // conv3 -> out ; BN3 ; add residual ; ReLU
    gemm64<<<dim3(NTILES, C1 / 64, B_), blk, 0, stream>>>(Ob, W3, nullptr, out, nullptr, C2, C1, 0);
    bn_stats<<<dim3(C1), blk, 0, stream>>>(out, m3, i3, C1);
    bn_add_relu<<<dim3(2048), blk, 0, stream>>>(out, x, g3, b3, m3, i3);

    (void)in_sizes; (void)n_in; (void)out_size; (void)ws_size;
}

// Round 6
// 497.455 us; speedup vs baseline: 2.9228x; 1.2993x over previous
//
#include <hip/hip_runtime.h>
#include <hip/hip_bf16.h>
#include <math.h>

#define B_ 4
#define C1 1024
#define C2 256
#define HEADS_ 4
#define N_ 2744
#define NT_ 10976
#define EPS_ 1e-5f

typedef float f32x4 __attribute__((ext_vector_type(4)));
typedef short bf16x8 __attribute__((ext_vector_type(8)));
typedef unsigned short us4 __attribute__((ext_vector_type(4)));

static __device__ __forceinline__ unsigned short bfbits(float x) {
    __hip_bfloat16 t = __float2bfloat16(x);
    unsigned short u; __builtin_memcpy(&u, &t, 2); return u;
}

// ---------------- prep: weights fp32->bf16, zero BN accumulators ----------------------
__global__ __launch_bounds__(256) void prep(
    const float* __restrict__ W1, const float* __restrict__ Wq, const float* __restrict__ Wk,
    const float* __restrict__ Wv, const float* __restrict__ W3,
    unsigned short* __restrict__ Wb, float* __restrict__ sums)
{
    const int bidx = blockIdx.x, t = threadIdx.x;
    if (bidx < 704) {
        const int i0 = (bidx * 256 + t) * 4;   // < 720896
        const float* src; int off;
        if (i0 < 262144)      { src = W1; off = i0; }
        else if (i0 < 327680) { src = Wq; off = i0 - 262144; }
        else if (i0 < 393216) { src = Wk; off = i0 - 327680; }
        else if (i0 < 458752) { src = Wv; off = i0 - 393216; }
        else                  { src = W3; off = i0 - 458752; }
        const float4 v = *(const float4*)&src[off];
        us4 pk; pk[0] = bfbits(v.x); pk[1] = bfbits(v.y); pk[2] = bfbits(v.z); pk[3] = bfbits(v.w);
        *(us4*)&Wb[i0] = pk;
    } else {
        float4 z; z.x = z.y = z.z = z.w = 0.f;
        *(float4*)&sums[t * 4] = z;   // 1024 floats (BN1 + BN2 accumulators)
    }
}

// ---------------- transpose + cvt: x [b][1024][N] f32 -> xT [b][N][1024] bf16 ---------
__global__ __launch_bounds__(256) void xt_kernel(const float* __restrict__ x,
                                                 unsigned short* __restrict__ xT)
{
    __shared__ float ld[64][65];
    const int b = blockIdx.z, c0 = blockIdx.y << 6, n0 = blockIdx.x << 6;
    const int t = threadIdx.x, tn = t & 63, tg = t >> 6;
    const int gn = n0 + tn;
#pragma unroll
    for (int i = 0; i < 16; ++i) {
        const int c = tg * 16 + i;
        ld[c][tn] = (gn < N_) ? x[((size_t)b * C1 + c0 + c) * N_ + gn] : 0.f;
    }
    __syncthreads();
#pragma unroll
    for (int i = 0; i < 16; ++i) {
        const int n = tg * 16 + i;
        if (n0 + n < N_)
            xT[((size_t)b * N_ + n0 + n) * C1 + c0 + tn] = bfbits(ld[tn][n]);
    }
}

// ---------------- MFMA GEMM: D[row][col] = sum_k A[row][k] * B[col][k] ----------------
// A [M][K] bf16 row-major, B [NC][K] bf16 row-major. BM=128, BN=64, BK=64, 4 waves.
// mode 0: f32 out0[z*oStride + row*ldc + col]
// mode 1: Q-proj: QAt[((z*4+h)*N+n)*128+d]=v, KBt[...+64+d]=v (bf16), bias[col]
// mode 2: K-proj: out0=KBt[...+d] (bf16), bias[col]
// mode 3: V-proj: rows=o, cols=n: out0 bf16 [(z*256+row)*N+col], bias[row]
__global__ __launch_bounds__(256, 4) void gemm_nt(
    const unsigned short* __restrict__ A, const unsigned short* __restrict__ Bm,
    const float* __restrict__ bias, void* __restrict__ out0, void* __restrict__ out1,
    int M, int NC, int K, long aStride, long bStride, long oStride, int ldc, int mode)
{
    __shared__ char smem[24576];   // As 128x128B, Bs 64x128B
    const int z = blockIdx.z;
    const int row0 = blockIdx.x << 7;
    const int col0 = blockIdx.y << 6;
    const unsigned short* Ag = A + (size_t)z * aStride;
    const unsigned short* Bg = Bm + (size_t)z * bStride;
    const int t = threadIdx.x;
    const int wave = t >> 6, lane = t & 63, l4 = lane >> 4, l15 = lane & 15;
    const int wr0 = wave << 5;

    f32x4 acc[2][4];
#pragma unroll
    for (int mi = 0; mi < 2; ++mi)
#pragma unroll
        for (int ks = 0; ks < 4; ++ks) acc[mi][ks] = (f32x4){0.f, 0.f, 0.f, 0.f};

    const int nk = K >> 6;
    for (int kt = 0; kt < nk; ++kt) {
        const int k0 = kt << 6;
        __syncthreads();
#pragma unroll
        for (int c = 0; c < 4; ++c) {   // A tile: 128 rows x 64 k
            const int e = c * 256 + t;
            const int r = e >> 3, ke = (e & 7) << 3;
            const int gr = min(row0 + r, M - 1);
            const bf16x8 v = *(const bf16x8*)(Ag + (size_t)gr * K + k0 + ke);
            *(bf16x8*)&smem[r * 128 + ((ke * 2) ^ ((r & 7) << 4))] = v;
        }
#pragma unroll
        for (int c = 0; c < 2; ++c) {   // B tile: 64 rows x 64 k
            const int e = c * 256 + t;
            const int r = e >> 3, ke = (e & 7) << 3;
            const int gr = min(col0 + r, NC - 1);
            const bf16x8 v = *(const bf16x8*)(Bg + (size_t)gr * K + k0 + ke);
            *(bf16x8*)&smem[16384 + r * 128 + ((ke * 2) ^ ((r & 7) << 4))] = v;
        }
        __syncthreads();
#pragma unroll
        for (int kc = 0; kc < 2; ++kc) {
            const int colb = kc * 64 + l4 * 16;
            const int ra0 = wr0 + l15, ra1 = wr0 + 16 + l15;
            const bf16x8 a0 = *(const bf16x8*)&smem[ra0 * 128 + (colb ^ ((ra0 & 7) << 4))];
            const bf16x8 a1 = *(const bf16x8*)&smem[ra1 * 128 + (colb ^ ((ra1 & 7) << 4))];
#pragma unroll
            for (int ks = 0; ks < 4; ++ks) {
                const int rb = ks * 16 + l15;
                const bf16x8 bf = *(const bf16x8*)&smem[16384 + rb * 128 + (colb ^ ((rb & 7) << 4))];
                acc[0][ks] = __builtin_amdgcn_mfma_f32_16x16x32_bf16(a0, bf, acc[0][ks], 0, 0, 0);
                acc[1][ks] = __builtin_amdgcn_mfma_f32_16x16x32_bf16(a1, bf, acc[1][ks], 0, 0, 0);
            }
        }
    }

    if (mode == 0) {
        float* o0 = (float*)out0 + (size_t)z * oStride;
#pragma unroll
        for (int mi = 0; mi < 2; ++mi)
#pragma unroll
            for (int ks = 0; ks < 4; ++ks)
#pragma unroll
                for (int j = 0; j < 4; ++j) {
                    const int row = row0 + wr0 + mi * 16 + l4 * 4 + j;
                    const int col = col0 + ks * 16 + l15;
                    if (row < M && col < NC) o0[(size_t)row * ldc + col] = acc[mi][ks][j];
                }
    } else if (mode == 3) {
        unsigned short* o0 = (unsigned short*)out0;
#pragma unroll
        for (int mi = 0; mi < 2; ++mi)
#pragma unroll
            for (int ks = 0; ks < 4; ++ks)
#pragma unroll
                for (int j = 0; j < 4; ++j) {
                    const int row = row0 + wr0 + mi * 16 + l4 * 4 + j;
                    const int col = col0 + ks * 16 + l15;
                    if (row < M && col < NC)
                        o0[((size_t)z * C2 + row) * N_ + col] = bfbits(acc[mi][ks][j] + bias[row]);
                }
    } else {
        unsigned short* yq = (unsigned short*)out0;
        unsigned short* yk = (unsigned short*)out1;
        const int h = col0 >> 6;
        const size_t bhbase = (size_t)(z * HEADS_ + h) * N_;
#pragma unroll
        for (int mi = 0; mi < 2; ++mi)
#pragma unroll
            for (int ks = 0; ks < 4; ++ks) {
                const int dcol = ks * 16 + l15;
                const float bvl = bias[col0 + dcol];
#pragma unroll
                for (int j = 0; j < 4; ++j) {
                    const int row = row0 + wr0 + mi * 16 + l4 * 4 + j;
                    if (row >= M) continue;
                    const unsigned short pv = bfbits(acc[mi][ks][j] + bvl);
                    if (mode == 1) {
                        yq[(bhbase + row) * 128 + dcol] = pv;
                        yk[(bhbase + row) * 128 + 64 + dcol] = pv;
                    } else {
                        yq[(bhbase + row) * 128 + dcol] = pv;
                    }
                }
            }
    }
}

// ---------------- BN stats over [rows][256] layout via atomics ------------------------
__global__ __launch_bounds__(256) void bn_stats_t(const float* __restrict__ Y,
                                                  float* __restrict__ sums)
{
    const int c = threadIdx.x;
    float s = 0.f, s2 = 0.f;
    for (int row = blockIdx.x; row < NT_; row += gridDim.x) {
        const float v = Y[(size_t)row * 256 + c];
        s += v; s2 += v * v;
    }
    atomicAdd(&sums[c], s);
    atomicAdd(&sums[256 + c], s2);
}

__global__ __launch_bounds__(256) void bn_finalize_t(const float* __restrict__ sums,
    const float* __restrict__ g, const float* __restrict__ bb, float* __restrict__ scsh)
{
    const int c = threadIdx.x;
    const float m = sums[c] * (1.f / NT_);
    const float var = sums[256 + c] * (1.f / NT_) - m * m;
    const float istd = rsqrtf(var + EPS_);
    const float sc = g[c] * istd;
    scsh[c] = sc;
    scsh[256 + c] = bb[c] - m * sc;
}

// ---------------- BN apply + ReLU + cvt: [rows][256] f32 -> bf16 ----------------------
__global__ __launch_bounds__(256) void bn_apply_t(const float* __restrict__ Y,
    const float* __restrict__ scsh, unsigned short* __restrict__ Yb)
{
    const int total4 = NT_ * 256 / 4;
    for (int i4 = blockIdx.x * 256 + threadIdx.x; i4 < total4; i4 += gridDim.x * 256) {
        const int i = i4 << 2;
        const int c0 = i & 255;
        const float4 v = *(const float4*)&Y[i];
        const float4 sc = *(const float4*)&scsh[c0];
        const float4 sh = *(const float4*)&scsh[256 + c0];
        us4 pk;
        pk[0] = bfbits(fmaxf(fmaf(v.x, sc.x, sh.x), 0.f));
        pk[1] = bfbits(fmaxf(fmaf(v.y, sc.y, sh.y), 0.f));
        pk[2] = bfbits(fmaxf(fmaf(v.z, sc.z, sh.z), 0.f));
        pk[3] = bfbits(fmaxf(fmaf(v.w, sc.w, sh.w), 0.f));
        *(us4*)&Yb[i] = pk;
    }
}

// ---------------- rel = rel_h + rel_w + rel_d into QAt cols 64..127 (bf16) ------------
__global__ __launch_bounds__(256) void rel_fill(
    const float* __restrict__ rh, const float* __restrict__ rw, const float* __restrict__ rd,
    unsigned short* __restrict__ QAt)
{
    const int idx = blockIdx.x * 256 + threadIdx.x;  // (h*16+dq)*N_ + n
    if (idx >= HEADS_ * 16 * N_) return;
    const int n = idx % N_;
    const int t2 = idx / N_;
    const int h = t2 >> 4, dq = t2 & 15;
    const int dd = n % 14;
    const int hh = (n / 14) % 14;
    const int w = n / 196;
    us4 pk;
#pragma unroll
    for (int i = 0; i < 4; ++i) {
        const int base = (h * 64 + dq * 4 + i) * 196;
        const float v = rh[base + hh * 14 + dd]
                      + rw[base + w * 14 + dd]
                      + rd[base + w * 14 + hh];
        pk[i] = bfbits(v);
    }
#pragma unroll
    for (int b = 0; b < B_; ++b)
        *(us4*)&QAt[((size_t)(b * HEADS_ + h) * N_ + n) * 128 + 64 + dq * 4] = pk;
}

// ---------------- MFMA flash attention, augmented head-dim 128 ------------------------
// LDS: Q [128][256B] @0 (32K), K [64][256B] @32768 (16K), P 4KB/wave @49152 (16K) = 64K
#define ALQ 0
#define ALK 32768
#define ALP 49152

__global__ __launch_bounds__(256, 2) void attn_mfma(
    const unsigned short* __restrict__ QAt, const unsigned short* __restrict__ KBt,
    const unsigned short* __restrict__ Vb, float* __restrict__ Ot)
{
    __shared__ char smem[65536];
    const int bid = blockIdx.x;                    // 352 = 8 XCD chunks of 44 (= 2 bh)
    const int sw = (bid & 7) * 44 + (bid >> 3);
    const int bh = sw / 22;
    const int ntile = sw - bh * 22;
    const int n0 = ntile << 7;
    const int b = bh >> 2, h = bh & 3;

    const unsigned short* qat = QAt + (size_t)bh * N_ * 128;
    const unsigned short* kbt = KBt + (size_t)bh * N_ * 128;
    const unsigned short* vb  = Vb + (size_t)(b * C2 + h * 64) * N_;
    float* ot = Ot + (size_t)b * N_ * 256 + h * 64;

    const int t = threadIdx.x;
    const int wave = t >> 6, lane = t & 63, l4 = lane >> 4, l15 = lane & 15;
    const int wq0 = wave << 5;

    // stage Q tile [128 q][128 dk]
#pragma unroll
    for (int c = 0; c < 8; ++c) {
        const int o = (c * 256 + t) * 16;
        const int q = o >> 8, cb = o & 255;
        const int gq = min(n0 + q, N_ - 1);
        const bf16x8 v = *(const bf16x8*)(qat + (size_t)gq * 128 + (cb >> 1));
        *(bf16x8*)&smem[ALQ + q * 256 + (cb ^ ((q & 7) << 4))] = v;
    }

    float m_r[2][4], l_r[2][4];
    f32x4 oacc[2][4];
#pragma unroll
    for (int mi = 0; mi < 2; ++mi)
#pragma unroll
        for (int j = 0; j < 4; ++j) { m_r[mi][j] = -1e30f; l_r[mi][j] = 0.f; }
#pragma unroll
    for (int mi = 0; mi < 2; ++mi)
#pragma unroll
        for (int ds = 0; ds < 4; ++ds) oacc[mi][ds] = (f32x4){0.f, 0.f, 0.f, 0.f};

    for (int kt = 0; kt < 43; ++kt) {
        const int m0 = kt << 6;
        // ---- stage K tile [64 m][128 dk]
#pragma unroll
        for (int c = 0; c < 4; ++c) {
            const int o = (c * 256 + t) * 16;
            const int r = o >> 8, cb = o & 255;
            const int gm = min(m0 + r, N_ - 1);
            const bf16x8 v = *(const bf16x8*)(kbt + (size_t)gm * 128 + (cb >> 1));
            *(bf16x8*)&smem[ALK + r * 256 + (cb ^ ((r & 7) << 4))] = v;
        }
        __syncthreads();
        // ---- V B-fragments straight from L2 into registers
        bf16x8 bvr[2][4];
#pragma unroll
        for (int mc = 0; mc < 2; ++mc)
#pragma unroll
            for (int ds = 0; ds < 4; ++ds) {
                const int ms = min(m0 + mc * 32 + l4 * 8, N_ - 8);
                bvr[mc][ds] = *(const bf16x8*)(vb + (size_t)(ds * 16 + l15) * N_ + ms);
            }
        // ---- QK^T: wave tile 32 q x 64 m, K=128
        f32x4 s[2][4];
#pragma unroll
        for (int mi = 0; mi < 2; ++mi)
#pragma unroll
            for (int ks = 0; ks < 4; ++ks) s[mi][ks] = (f32x4){0.f, 0.f, 0.f, 0.f};
#pragma unroll
        for (int kc = 0; kc < 4; ++kc) {
            const int colb = kc * 64 + l4 * 16;
            const int q0r = wq0 + l15;
            const int q1r = wq0 + 16 + l15;
            const bf16x8 a0 = *(const bf16x8*)&smem[ALQ + q0r * 256 + (colb ^ ((q0r & 7) << 4))];
            const bf16x8 a1 = *(const bf16x8*)&smem[ALQ + q1r * 256 + (colb ^ ((q1r & 7) << 4))];
#pragma unroll
            for (int ks = 0; ks < 4; ++ks) {
                const int r = ks * 16 + l15;
                const bf16x8 bf = *(const bf16x8*)&smem[ALK + r * 256 + (colb ^ ((r & 7) << 4))];
                s[0][ks] = __builtin_amdgcn_mfma_f32_16x16x32_bf16(a0, bf, s[0][ks], 0, 0, 0);
                s[1][ks] = __builtin_amdgcn_mfma_f32_16x16x32_bf16(a1, bf, s[1][ks], 0, 0, 0);
            }
        }
        if (m0 + 64 > N_) {
#pragma unroll
            for (int ks = 0; ks < 4; ++ks)
                if (m0 + ks * 16 + l15 >= N_) {
                    s[0][ks] = (f32x4){-1e30f, -1e30f, -1e30f, -1e30f};
                    s[1][ks] = (f32x4){-1e30f, -1e30f, -1e30f, -1e30f};
                }
        }
        // ---- online softmax (row = mi*16 + l4*4 + j, cols across 16 lanes)
        const int pbase = ALP + (wave << 12);
#pragma unroll
        for (int mi = 0; mi < 2; ++mi) {
#pragma unroll
            for (int j = 0; j < 4; ++j) {
                const float v0 = s[mi][0][j], v1 = s[mi][1][j];
                const float v2 = s[mi][2][j], v3 = s[mi][3][j];
                float rmax = fmaxf(fmaxf(v0, v1), fmaxf(v2, v3));
                rmax = fmaxf(rmax, __shfl_xor(rmax, 1, 64));
                rmax = fmaxf(rmax, __shfl_xor(rmax, 2, 64));
                rmax = fmaxf(rmax, __shfl_xor(rmax, 4, 64));
                rmax = fmaxf(rmax, __shfl_xor(rmax, 8, 64));
                const float mnew = fmaxf(m_r[mi][j], rmax);
                const float p0 = __expf(v0 - mnew), p1 = __expf(v1 - mnew);
                const float p2 = __expf(v2 - mnew), p3 = __expf(v3 - mnew);
                float ps = p0 + p1 + p2 + p3;
                ps += __shfl_xor(ps, 1, 64);
                ps += __shfl_xor(ps, 2, 64);
                ps += __shfl_xor(ps, 4, 64);
                ps += __shfl_xor(ps, 8, 64);
                const float scl = __expf(m_r[mi][j] - mnew);
                m_r[mi][j] = mnew;
                l_r[mi][j] = l_r[mi][j] * scl + ps;
                oacc[mi][0][j] *= scl; oacc[mi][1][j] *= scl;
                oacc[mi][2][j] *= scl; oacc[mi][3][j] *= scl;
                const int r = mi * 16 + l4 * 4 + j;
                const int rb = pbase + r * 128, sz = (r & 7) << 4;
                *(unsigned short*)&smem[rb + ((l15 * 2 +  0) ^ sz)] = bfbits(p0);
                *(unsigned short*)&smem[rb + ((l15 * 2 + 32) ^ sz)] = bfbits(p1);
                *(unsigned short*)&smem[rb + ((l15 * 2 + 64) ^ sz)] = bfbits(p2);
                *(unsigned short*)&smem[rb + ((l15 * 2 + 96) ^ sz)] = bfbits(p3);
            }
        }
        // ---- PV: O[32 q][64 d] += P[32 q][64 m] * V
#pragma unroll
        for (int mc = 0; mc < 2; ++mc) {
            const int colb = mc * 64 + l4 * 16;
            const int r0 = l15, r1 = 16 + l15;
            const bf16x8 pa0 = *(const bf16x8*)&smem[pbase + r0 * 128 + (colb ^ ((r0 & 7) << 4))];
            const bf16x8 pa1 = *(const bf16x8*)&smem[pbase + r1 * 128 + (colb ^ ((r1 & 7) << 4))];
#pragma unroll
            for (int ds = 0; ds < 4; ++ds) {
                oacc[0][ds] = __builtin_amdgcn_mfma_f32_16x16x32_bf16(pa0, bvr[mc][ds], oacc[0][ds], 0, 0, 0);
                oacc[1][ds] = __builtin_amdgcn_mfma_f32_16x16x32_bf16(pa1, bvr[mc][ds], oacc[1][ds], 0, 0, 0);
            }
        }
        __syncthreads();
    }

    // ---- epilogue: Ot[b][n][256] = O / l
#pragma unroll
    for (int mi = 0; mi < 2; ++mi)
#pragma unroll
        for (int j = 0; j < 4; ++j) {
            const int n = n0 + wq0 + mi * 16 + l4 * 4 + j;
            if (n < N_) {
                const float inv = 1.f / l_r[mi][j];
#pragma unroll
                for (int ds = 0; ds < 4; ++ds)
                    ot[(size_t)n * 256 + ds * 16 + l15] = oacc[mi][ds][j] * inv;
            }
        }
}

// ---------------- BN3 stats: one block per channel over out [b][1024][N] --------------
__global__ __launch_bounds__(256) void bn_stats(const float* __restrict__ Y,
                                                float* __restrict__ mean, float* __restrict__ istd,
                                                int Cch)
{
    const int ch = blockIdx.x;
    float s = 0.f, s2 = 0.f;
    for (int i = threadIdx.x; i < NT_; i += 256) {
        const int b = i / N_, n = i - b * N_;
        const float v = Y[((size_t)b * Cch + ch) * N_ + n];
        s += v; s2 += v * v;
    }
#pragma unroll
    for (int off = 32; off > 0; off >>= 1) {
        s  += __shfl_down(s, off, 64);
        s2 += __shfl_down(s2, off, 64);
    }
    __shared__ float red[8];
    const int wid = threadIdx.x >> 6;
    if ((threadIdx.x & 63) == 0) { red[wid] = s; red[4 + wid] = s2; }
    __syncthreads();
    if (threadIdx.x == 0) {
        s = red[0] + red[1] + red[2] + red[3];
        s2 = red[4] + red[5] + red[6] + red[7];
        const float m = s / (float)NT_;
        const float var = s2 / (float)NT_ - m * m;
        mean[ch] = m;
        istd[ch] = rsqrtf(var + EPS_);
    }
}

// ---------------- final: out = relu(bn3(out) + x), in place ---------------------------
__global__ __launch_bounds__(256) void bn_add_relu(float* __restrict__ Y, const float* __restrict__ X,
    const float* __restrict__ g, const float* __restrict__ bt,
    const float* __restrict__ mean, const float* __restrict__ istd)
{
    const int total4 = B_ * C1 * (N_ / 4);
    for (int i4 = blockIdx.x * 256 + threadIdx.x; i4 < total4; i4 += gridDim.x * 256) {
        const int i = i4 << 2;
        const int ch = (i / N_) % C1;
        const float sc = g[ch] * istd[ch];
        const float sh = bt[ch] - mean[ch] * sc;
        float4 y = *(float4*)&Y[i];
        const float4 x = *(const float4*)&X[i];
        y.x = fmaxf(fmaf(y.x, sc, sh) + x.x, 0.f);
        y.y = fmaxf(fmaf(y.y, sc, sh) + x.y, 0.f);
        y.z = fmaxf(fmaf(y.z, sc, sh) + x.z, 0.f);
        y.w = fmaxf(fmaf(y.w, sc, sh) + x.w, 0.f);
        *(float4*)&Y[i] = y;
    }
}

extern "C" void kernel_launch(void* const* d_in, const int* in_sizes, int n_in,
                              void* d_out, int out_size, void* d_ws, size_t ws_size,
                              hipStream_t stream)
{
    const float* x  = (const float*)d_in[0];
    const float* W1 = (const float*)d_in[1];
    const float* g1 = (const float*)d_in[2];
    const float* b1 = (const float*)d_in[3];
    const float* Wq = (const float*)d_in[4];
    const float* bq = (const float*)d_in[5];
    const float* Wk = (const float*)d_in[6];
    const float* bk = (const float*)d_in[7];
    const float* Wv = (const float*)d_in[8];
    const float* bv = (const float*)d_in[9];
    const float* rh = (const float*)d_in[10];
    const float* rw = (const float*)d_in[11];
    const float* rd = (const float*)d_in[12];
    const float* g2 = (const float*)d_in[13];
    const float* b2 = (const float*)d_in[14];
    const float* W3 = (const float*)d_in[15];
    const float* g3 = (const float*)d_in[16];
    const float* b3 = (const float*)d_in[17];
    float* out = (float*)d_out;

    float* ws = (float*)d_ws;
    // region A (5,619,712 f32): xT, later QAt+KBt
    unsigned short* xT  = (unsigned short*)ws;
    unsigned short* QAt = (unsigned short*)ws;                 // 2,809,856 f32
    unsigned short* KBt = (unsigned short*)(ws + 2809856);     // 2,809,856 f32
    // region B (2,809,856 f32): Y1t f32, later Ot f32
    float* Y1t = ws + 5619712;
    float* Ot  = Y1t;
    // region C (1,404,928 f32): Y1t16, later Obt16
    unsigned short* Y1t16 = (unsigned short*)(ws + 8429568);
    unsigned short* Obt16 = Y1t16;
    // region D (1,404,928 f32): Vb16
    unsigned short* Vb16 = (unsigned short*)(ws + 9834496);
    // region E (360,448 f32): bf16 weights
    unsigned short* Wb = (unsigned short*)(ws + 11239424);
    unsigned short* W1b = Wb;
    unsigned short* Wqb = Wb + 262144;
    unsigned short* Wkb = Wb + 327680;
    unsigned short* Wvb = Wb + 393216;
    unsigned short* W3b = Wb + 458752;
    // region F: stats
    float* st = ws + 11599872;
    float* sums1 = st;             // 512
    float* sums2 = st + 512;       // 512
    float* scsh1 = st + 1024;      // 512
    float* scsh2 = st + 1536;      // 512
    float* m3 = st + 2048;         // 1024
    float* i3 = st + 3072;         // 1024

    dim3 blk(256);

    prep<<<dim3(705), blk, 0, stream>>>(W1, Wq, Wk, Wv, W3, Wb, sums1);
    xt_kernel<<<dim3(43, 16, B_), blk, 0, stream>>>(x, xT);

    // conv1: D[n][o] f32 -> Y1t
    gemm_nt<<<dim3(22, 4, B_), blk, 0, stream>>>(xT, W1b, nullptr, Y1t, nullptr,
        N_, 256, 1024, (long)N_ * 1024, 0, (long)N_ * 256, 256, 0);
    bn_stats_t<<<dim3(128), blk, 0, stream>>>(Y1t, sums1);
    bn_finalize_t<<<dim3(1), blk, 0, stream>>>(sums1, g1, b1, scsh1);
    bn_apply_t<<<dim3(1024), blk, 0, stream>>>(Y1t, scsh1, Y1t16);

    rel_fill<<<dim3((HEADS_ * 16 * N_ + 255) / 256), blk, 0, stream>>>(rh, rw, rd, QAt);

    // Q/K/V projections
    gemm_nt<<<dim3(22, 4, B_), blk, 0, stream>>>(Y1t16, Wqb, bq, QAt, KBt,
        N_, 256, 256, (long)N_ * 256, 0, 0, 0, 1);
    gemm_nt<<<dim3(22, 4, B_), blk, 0, stream>>>(Y1t16, Wkb, bk, KBt, nullptr,
        N_, 256, 256, (long)N_ * 256, 0, 0, 0, 2);
    gemm_nt<<<dim3(2, 43, B_), blk, 0, stream>>>(Wvb, Y1t16, bv, Vb16, nullptr,
        256, N_, 256, 0, (long)N_ * 256, 0, 0, 3);

    // flash attention -> Ot [b][n][256] f32
    attn_mfma<<<dim3(352), blk, 0, stream>>>(QAt, KBt, Vb16, Ot);

    // BN2 + ReLU -> Obt16
    bn_stats_t<<<dim3(128), blk, 0, stream>>>(Ot, sums2);
    bn_finalize_t<<<dim3(1), blk, 0, stream>>>(sums2, g2, b2, scsh2);
    bn_apply_t<<<dim3(1024), blk, 0, stream>>>(Ot, scsh2, Obt16);

    // conv3: D[o][n] f32 -> out
    gemm_nt<<<dim3(8, 43, B_), blk, 0, stream>>>(W3b, Obt16, nullptr, out, nullptr,
        1024, N_, 256, 0, (long)N_ * 256, (long)C1 * N_, N_, 0);
    bn_stats<<<dim3(C1), blk, 0, stream>>>(out, m3, i3, C1);
    bn_add_relu<<<dim3(2048), blk, 0, stream>>>(out, x, g3, b3, m3, i3);

    (void)in_sizes; (void)n_in; (void)out_size; (void)ws_size;
}

// Round 7
// 470.032 us; speedup vs baseline: 3.0933x; 1.0583x over previous
//
#include <hip/hip_runtime.h>
#include <hip/hip_bf16.h>
#include <math.h>

#define B_ 4
#define C1 1024
#define C2 256
#define HEADS_ 4
#define N_ 2744
#define NT_ 10976
#define EPS_ 1e-5f

typedef float f32x4 __attribute__((ext_vector_type(4)));
typedef short bf16x8 __attribute__((ext_vector_type(8)));
typedef unsigned short us4 __attribute__((ext_vector_type(4)));

static __device__ __forceinline__ unsigned short bfbits(float x) {
    __hip_bfloat16 t = __float2bfloat16(x);
    unsigned short u; __builtin_memcpy(&u, &t, 2); return u;
}

// ---------------- prep: weights fp32->bf16, zero BN accumulators ----------------------
__global__ __launch_bounds__(256) void prep(
    const float* __restrict__ W1, const float* __restrict__ Wq, const float* __restrict__ Wk,
    const float* __restrict__ Wv, const float* __restrict__ W3,
    unsigned short* __restrict__ Wb, float* __restrict__ sums)
{
    const int bidx = blockIdx.x, t = threadIdx.x;
    if (bidx < 704) {
        const int i0 = (bidx * 256 + t) * 4;   // < 720896
        const float* src; int off;
        if (i0 < 262144)      { src = W1; off = i0; }
        else if (i0 < 327680) { src = Wq; off = i0 - 262144; }
        else if (i0 < 393216) { src = Wk; off = i0 - 327680; }
        else if (i0 < 458752) { src = Wv; off = i0 - 393216; }
        else                  { src = W3; off = i0 - 458752; }
        const float4 v = *(const float4*)&src[off];
        us4 pk; pk[0] = bfbits(v.x); pk[1] = bfbits(v.y); pk[2] = bfbits(v.z); pk[3] = bfbits(v.w);
        *(us4*)&Wb[i0] = pk;
    } else {
        float4 z; z.x = z.y = z.z = z.w = 0.f;
        *(float4*)&sums[t * 4] = z;   // 1024 floats (BN1 + BN2 accumulators)
    }
}

// ---------------- transpose + cvt: x [b][1024][N] f32 -> xT [b][N][1024] bf16 ---------
__global__ __launch_bounds__(256) void xt_kernel(const float* __restrict__ x,
                                                 unsigned short* __restrict__ xT)
{
    __shared__ float ld[64][65];
    const int b = blockIdx.z, c0 = blockIdx.y << 6, n0 = blockIdx.x << 6;
    const int t = threadIdx.x, tn = t & 63, tg = t >> 6;
    const int gn = n0 + tn;
#pragma unroll
    for (int i = 0; i < 16; ++i) {
        const int c = tg * 16 + i;
        ld[c][tn] = (gn < N_) ? x[((size_t)b * C1 + c0 + c) * N_ + gn] : 0.f;
    }
    __syncthreads();
#pragma unroll
    for (int i = 0; i < 16; ++i) {
        const int n = tg * 16 + i;
        if (n0 + n < N_)
            xT[((size_t)b * N_ + n0 + n) * C1 + c0 + tn] = bfbits(ld[tn][n]);
    }
}

// ---------------- MFMA GEMM: D[row][col] = sum_k A[row][k] * B[col][k] ----------------
// A [M][K] bf16 row-major, B [NC][K] bf16 row-major. BM=128, BN=64, BK=64, 4 waves.
// mode 0: f32 out0[z*oStride + row*ldc + col]
// mode 1: fused QK-proj (NC=512): col<256 -> Q: QAt[((z*4+h)*N+n)*128+d], KBt[...+64+d],
//          bias=bias0[col]; col>=256 -> K: KBt[...+d], bias=bias1[col-256]
// mode 3: V-proj: rows=o, cols=n: out0 bf16 [(z*256+row)*N+col], bias0[row]
__global__ __launch_bounds__(256, 4) void gemm_nt(
    const unsigned short* __restrict__ A, const unsigned short* __restrict__ Bm,
    const float* __restrict__ bias0, const float* __restrict__ bias1,
    void* __restrict__ out0, void* __restrict__ out1,
    int M, int NC, int K, long aStride, long bStride, long oStride, int ldc, int mode)
{
    __shared__ char smem[24576];   // As 128x128B, Bs 64x128B
    const int z = blockIdx.z;
    const int row0 = blockIdx.x << 7;
    const int col0 = blockIdx.y << 6;
    const unsigned short* Ag = A + (size_t)z * aStride;
    const unsigned short* Bg = Bm + (size_t)z * bStride;
    const int t = threadIdx.x;
    const int wave = t >> 6, lane = t & 63, l4 = lane >> 4, l15 = lane & 15;
    const int wr0 = wave << 5;

    f32x4 acc[2][4];
#pragma unroll
    for (int mi = 0; mi < 2; ++mi)
#pragma unroll
        for (int ks = 0; ks < 4; ++ks) acc[mi][ks] = (f32x4){0.f, 0.f, 0.f, 0.f};

    const int nk = K >> 6;
    for (int kt = 0; kt < nk; ++kt) {
        const int k0 = kt << 6;
        __syncthreads();
#pragma unroll
        for (int c = 0; c < 4; ++c) {   // A tile: 128 rows x 64 k
            const int e = c * 256 + t;
            const int r = e >> 3, ke = (e & 7) << 3;
            const int gr = min(row0 + r, M - 1);
            const bf16x8 v = *(const bf16x8*)(Ag + (size_t)gr * K + k0 + ke);
            *(bf16x8*)&smem[r * 128 + ((ke * 2) ^ ((r & 7) << 4))] = v;
        }
#pragma unroll
        for (int c = 0; c < 2; ++c) {   // B tile: 64 rows x 64 k
            const int e = c * 256 + t;
            const int r = e >> 3, ke = (e & 7) << 3;
            const int gr = min(col0 + r, NC - 1);
            const bf16x8 v = *(const bf16x8*)(Bg + (size_t)gr * K + k0 + ke);
            *(bf16x8*)&smem[16384 + r * 128 + ((ke * 2) ^ ((r & 7) << 4))] = v;
        }
        __syncthreads();
#pragma unroll
        for (int kc = 0; kc < 2; ++kc) {
            const int colb = kc * 64 + l4 * 16;
            const int ra0 = wr0 + l15, ra1 = wr0 + 16 + l15;
            const bf16x8 a0 = *(const bf16x8*)&smem[ra0 * 128 + (colb ^ ((ra0 & 7) << 4))];
            const bf16x8 a1 = *(const bf16x8*)&smem[ra1 * 128 + (colb ^ ((ra1 & 7) << 4))];
#pragma unroll
            for (int ks = 0; ks < 4; ++ks) {
                const int rb = ks * 16 + l15;
                const bf16x8 bf = *(const bf16x8*)&smem[16384 + rb * 128 + (colb ^ ((rb & 7) << 4))];
                acc[0][ks] = __builtin_amdgcn_mfma_f32_16x16x32_bf16(a0, bf, acc[0][ks], 0, 0, 0);
                acc[1][ks] = __builtin_amdgcn_mfma_f32_16x16x32_bf16(a1, bf, acc[1][ks], 0, 0, 0);
            }
        }
    }

    if (mode == 0) {
        float* o0 = (float*)out0 + (size_t)z * oStride;
#pragma unroll
        for (int mi = 0; mi < 2; ++mi)
#pragma unroll
            for (int ks = 0; ks < 4; ++ks)
#pragma unroll
                for (int j = 0; j < 4; ++j) {
                    const int row = row0 + wr0 + mi * 16 + l4 * 4 + j;
                    const int col = col0 + ks * 16 + l15;
                    if (row < M && col < NC) o0[(size_t)row * ldc + col] = acc[mi][ks][j];
                }
    } else if (mode == 3) {
        unsigned short* o0 = (unsigned short*)out0;
#pragma unroll
        for (int mi = 0; mi < 2; ++mi)
#pragma unroll
            for (int ks = 0; ks < 4; ++ks)
#pragma unroll
                for (int j = 0; j < 4; ++j) {
                    const int row = row0 + wr0 + mi * 16 + l4 * 4 + j;
                    const int col = col0 + ks * 16 + l15;
                    if (row < M && col < NC)
                        o0[((size_t)z * C2 + row) * N_ + col] = bfbits(acc[mi][ks][j] + bias0[row]);
                }
    } else {
        // fused QK epilogue
        unsigned short* yq = (unsigned short*)out0;
        unsigned short* yk = (unsigned short*)out1;
        const bool isQ = col0 < 256;
        const int hcol = (isQ ? col0 : col0 - 256) >> 6;
        const size_t bhbase = (size_t)(z * HEADS_ + hcol) * N_;
#pragma unroll
        for (int mi = 0; mi < 2; ++mi)
#pragma unroll
            for (int ks = 0; ks < 4; ++ks) {
                const int d = ks * 16 + l15;           // 0..63 within head
                const int col = col0 + d;
                const float bvl = isQ ? bias0[col] : bias1[col - 256];
#pragma unroll
                for (int j = 0; j < 4; ++j) {
                    const int row = row0 + wr0 + mi * 16 + l4 * 4 + j;
                    if (row >= M) continue;
                    const unsigned short pv = bfbits(acc[mi][ks][j] + bvl);
                    if (isQ) {
                        yq[(bhbase + row) * 128 + d] = pv;
                        yk[(bhbase + row) * 128 + 64 + d] = pv;
                    } else {
                        yk[(bhbase + row) * 128 + d] = pv;
                    }
                }
            }
    }
}

// ---------------- BN stats over [rows][256] layout via atomics ------------------------
__global__ __launch_bounds__(256) void bn_stats_t(const float* __restrict__ Y,
                                                  float* __restrict__ sums)
{
    const int c = threadIdx.x;
    float s = 0.f, s2 = 0.f;
    for (int row = blockIdx.x; row < NT_; row += gridDim.x) {
        const float v = Y[(size_t)row * 256 + c];
        s += v; s2 += v * v;
    }
    atomicAdd(&sums[c], s);
    atomicAdd(&sums[256 + c], s2);
}

__global__ __launch_bounds__(256) void bn_finalize_t(const float* __restrict__ sums,
    const float* __restrict__ g, const float* __restrict__ bb, float* __restrict__ scsh)
{
    const int c = threadIdx.x;
    const float m = sums[c] * (1.f / NT_);
    const float var = sums[256 + c] * (1.f / NT_) - m * m;
    const float istd = rsqrtf(var + EPS_);
    const float sc = g[c] * istd;
    scsh[c] = sc;
    scsh[256 + c] = bb[c] - m * sc;
}

// ---------------- BN apply + ReLU + cvt: [rows][256] f32 -> bf16 ----------------------
__global__ __launch_bounds__(256) void bn_apply_t(const float* __restrict__ Y,
    const float* __restrict__ scsh, unsigned short* __restrict__ Yb)
{
    const int total4 = NT_ * 256 / 4;
    for (int i4 = blockIdx.x * 256 + threadIdx.x; i4 < total4; i4 += gridDim.x * 256) {
        const int i = i4 << 2;
        const int c0 = i & 255;
        const float4 v = *(const float4*)&Y[i];
        const float4 sc = *(const float4*)&scsh[c0];
        const float4 sh = *(const float4*)&scsh[256 + c0];
        us4 pk;
        pk[0] = bfbits(fmaxf(fmaf(v.x, sc.x, sh.x), 0.f));
        pk[1] = bfbits(fmaxf(fmaf(v.y, sc.y, sh.y), 0.f));
        pk[2] = bfbits(fmaxf(fmaf(v.z, sc.z, sh.z), 0.f));
        pk[3] = bfbits(fmaxf(fmaf(v.w, sc.w, sh.w), 0.f));
        *(us4*)&Yb[i] = pk;
    }
}

// ---------------- rel = rel_h + rel_w + rel_d into QAt cols 64..127 (bf16) ------------
__global__ __launch_bounds__(256) void rel_fill(
    const float* __restrict__ rh, const float* __restrict__ rw, const float* __restrict__ rd,
    unsigned short* __restrict__ QAt)
{
    const int idx = blockIdx.x * 256 + threadIdx.x;  // (h*16+dq)*N_ + n
    if (idx >= HEADS_ * 16 * N_) return;
    const int n = idx % N_;
    const int t2 = idx / N_;
    const int h = t2 >> 4, dq = t2 & 15;
    const int dd = n % 14;
    const int hh = (n / 14) % 14;
    const int w = n / 196;
    us4 pk;
#pragma unroll
    for (int i = 0; i < 4; ++i) {
        const int base = (h * 64 + dq * 4 + i) * 196;
        const float v = rh[base + hh * 14 + dd]
                      + rw[base + w * 14 + dd]
                      + rd[base + w * 14 + hh];
        pk[i] = bfbits(v);
    }
#pragma unroll
    for (int b = 0; b < B_; ++b)
        *(us4*)&QAt[((size_t)(b * HEADS_ + h) * N_ + n) * 128 + 64 + dq * 4] = pk;
}

// ---------------- MFMA flash attention, augmented head-dim 128 ------------------------
// QB=64, 4 waves x 16 q-rows. LDS: Q [64][256B] @0 (16K), K [64][256B] @16384 (16K),
// P 2K/wave @32768 (8K) = 40960 B -> 4 blocks/CU.
#define ALQ 0
#define ALK 16384
#define ALP 32768

__global__ __launch_bounds__(256, 4) void attn_mfma(
    const unsigned short* __restrict__ QAt, const unsigned short* __restrict__ KBt,
    const unsigned short* __restrict__ Vb, float* __restrict__ Ot)
{
    __shared__ char smem[40960];
    const int bid = blockIdx.x;                    // 688 = 8 XCD chunks of 86
    const int sw = (bid & 7) * 86 + (bid >> 3);
    const int bh = sw / 43;
    const int ntile = sw - bh * 43;
    const int n0 = ntile << 6;
    const int b = bh >> 2, h = bh & 3;

    const unsigned short* qat = QAt + (size_t)bh * N_ * 128;
    const unsigned short* kbt = KBt + (size_t)bh * N_ * 128;
    const unsigned short* vb  = Vb + (size_t)(b * C2 + h * 64) * N_;
    float* ot = Ot + (size_t)b * N_ * 256 + h * 64;

    const int t = threadIdx.x;
    const int wave = t >> 6, lane = t & 63, l4 = lane >> 4, l15 = lane & 15;
    const int wq0 = wave << 4;

    // stage Q tile [64 q][128 dk]
#pragma unroll
    for (int c = 0; c < 4; ++c) {
        const int o = (c * 256 + t) * 16;
        const int q = o >> 8, cb = o & 255;
        const int gq = min(n0 + q, N_ - 1);
        const bf16x8 v = *(const bf16x8*)(qat + (size_t)gq * 128 + (cb >> 1));
        *(bf16x8*)&smem[ALQ + q * 256 + (cb ^ ((q & 7) << 4))] = v;
    }

    float m_r[4], l_r[4];
    f32x4 oacc[4];
#pragma unroll
    for (int j = 0; j < 4; ++j) { m_r[j] = -1e30f; l_r[j] = 0.f; }
#pragma unroll
    for (int ds = 0; ds < 4; ++ds) oacc[ds] = (f32x4){0.f, 0.f, 0.f, 0.f};

    const int pbase = ALP + (wave << 11);

    for (int kt = 0; kt < 43; ++kt) {
        const int m0 = kt << 6;
        // ---- stage K tile [64 m][128 dk]
#pragma unroll
        for (int c = 0; c < 4; ++c) {
            const int o = (c * 256 + t) * 16;
            const int r = o >> 8, cb = o & 255;
            const int gm = min(m0 + r, N_ - 1);
            const bf16x8 v = *(const bf16x8*)(kbt + (size_t)gm * 128 + (cb >> 1));
            *(bf16x8*)&smem[ALK + r * 256 + (cb ^ ((r & 7) << 4))] = v;
        }
        __syncthreads();
        // ---- V B-fragments straight from L2 into registers
        bf16x8 bvr[2][4];
#pragma unroll
        for (int mc = 0; mc < 2; ++mc)
#pragma unroll
            for (int ds = 0; ds < 4; ++ds) {
                const int ms = min(m0 + mc * 32 + l4 * 8, N_ - 8);
                bvr[mc][ds] = *(const bf16x8*)(vb + (size_t)(ds * 16 + l15) * N_ + ms);
            }
        // ---- QK^T: wave tile 16 q x 64 m, K=128
        f32x4 s[4];
#pragma unroll
        for (int ks = 0; ks < 4; ++ks) s[ks] = (f32x4){0.f, 0.f, 0.f, 0.f};
#pragma unroll
        for (int kc = 0; kc < 4; ++kc) {
            const int colb = kc * 64 + l4 * 16;
            const int qr = wq0 + l15;
            const bf16x8 a0 = *(const bf16x8*)&smem[ALQ + qr * 256 + (colb ^ ((qr & 7) << 4))];
#pragma unroll
            for (int ks = 0; ks < 4; ++ks) {
                const int r = ks * 16 + l15;
                const bf16x8 bf = *(const bf16x8*)&smem[ALK + r * 256 + (colb ^ ((r & 7) << 4))];
                s[ks] = __builtin_amdgcn_mfma_f32_16x16x32_bf16(a0, bf, s[ks], 0, 0, 0);
            }
        }
        if (m0 + 64 > N_) {
#pragma unroll
            for (int ks = 0; ks < 4; ++ks)
                if (m0 + ks * 16 + l15 >= N_)
                    s[ks] = (f32x4){-1e30f, -1e30f, -1e30f, -1e30f};
        }
        // ---- online softmax (row = l4*4 + j, 64 cols across 16 lanes x 4 ks)
#pragma unroll
        for (int j = 0; j < 4; ++j) {
            const float v0 = s[0][j], v1 = s[1][j];
            const float v2 = s[2][j], v3 = s[3][j];
            float rmax = fmaxf(fmaxf(v0, v1), fmaxf(v2, v3));
            rmax = fmaxf(rmax, __shfl_xor(rmax, 1, 64));
            rmax = fmaxf(rmax, __shfl_xor(rmax, 2, 64));
            rmax = fmaxf(rmax, __shfl_xor(rmax, 4, 64));
            rmax = fmaxf(rmax, __shfl_xor(rmax, 8, 64));
            const float mnew = fmaxf(m_r[j], rmax);
            const float p0 = __expf(v0 - mnew), p1 = __expf(v1 - mnew);
            const float p2 = __expf(v2 - mnew), p3 = __expf(v3 - mnew);
            float ps = p0 + p1 + p2 + p3;
            ps += __shfl_xor(ps, 1, 64);
            ps += __shfl_xor(ps, 2, 64);
            ps += __shfl_xor(ps, 4, 64);
            ps += __shfl_xor(ps, 8, 64);
            const float scl = __expf(m_r[j] - mnew);
            m_r[j] = mnew;
            l_r[j] = l_r[j] * scl + ps;
            oacc[0][j] *= scl; oacc[1][j] *= scl;
            oacc[2][j] *= scl; oacc[3][j] *= scl;
            const int r = l4 * 4 + j;
            const int rb = pbase + r * 128, sz = (r & 7) << 4;
            *(unsigned short*)&smem[rb + ((l15 * 2 +  0) ^ sz)] = bfbits(p0);
            *(unsigned short*)&smem[rb + ((l15 * 2 + 32) ^ sz)] = bfbits(p1);
            *(unsigned short*)&smem[rb + ((l15 * 2 + 64) ^ sz)] = bfbits(p2);
            *(unsigned short*)&smem[rb + ((l15 * 2 + 96) ^ sz)] = bfbits(p3);
        }
        // ---- PV: O[16 q][64 d] += P[16 q][64 m] * V  (P is per-wave region, no barrier)
#pragma unroll
        for (int mc = 0; mc < 2; ++mc) {
            const int colb = mc * 64 + l4 * 16;
            const int r0 = l15;
            const bf16x8 pa0 = *(const bf16x8*)&smem[pbase + r0 * 128 + (colb ^ ((r0 & 7) << 4))];
#pragma unroll
            for (int ds = 0; ds < 4; ++ds) {
                oacc[ds] = __builtin_amdgcn_mfma_f32_16x16x32_bf16(pa0, bvr[mc][ds], oacc[ds], 0, 0, 0);
            }
        }
        __syncthreads();
    }

    // ---- epilogue: Ot[b][n][256] = O / l
#pragma unroll
    for (int j = 0; j < 4; ++j) {
        const int n = n0 + wq0 + l4 * 4 + j;
        if (n < N_) {
            const float inv = 1.f / l_r[j];
#pragma unroll
            for (int ds = 0; ds < 4; ++ds)
                ot[(size_t)n * 256 + ds * 16 + l15] = oacc[ds][j] * inv;
        }
    }
}

// ---------------- BN3 stats: one block per channel over out [b][1024][N] --------------
__global__ __launch_bounds__(256) void bn_stats(const float* __restrict__ Y,
                                                float* __restrict__ mean, float* __restrict__ istd,
                                                int Cch)
{
    const int ch = blockIdx.x;
    float s = 0.f, s2 = 0.f;
    for (int i = threadIdx.x; i < NT_; i += 256) {
        const int b = i / N_, n = i - b * N_;
        const float v = Y[((size_t)b * Cch + ch) * N_ + n];
        s += v; s2 += v * v;
    }
#pragma unroll
    for (int off = 32; off > 0; off >>= 1) {
        s  += __shfl_down(s, off, 64);
        s2 += __shfl_down(s2, off, 64);
    }
    __shared__ float red[8];
    const int wid = threadIdx.x >> 6;
    if ((threadIdx.x & 63) == 0) { red[wid] = s; red[4 + wid] = s2; }
    __syncthreads();
    if (threadIdx.x == 0) {
        s = red[0] + red[1] + red[2] + red[3];
        s2 = red[4] + red[5] + red[6] + red[7];
        const float m = s / (float)NT_;
        const float var = s2 / (float)NT_ - m * m;
        mean[ch] = m;
        istd[ch] = rsqrtf(var + EPS_);
    }
}

// ---------------- final: out = relu(bn3(out) + x), in place ---------------------------
__global__ __launch_bounds__(256) void bn_add_relu(float* __restrict__ Y, const float* __restrict__ X,
    const float* __restrict__ g, const float* __restrict__ bt,
    const float* __restrict__ mean, const float* __restrict__ istd)
{
    const int total4 = B_ * C1 * (N_ / 4);
    for (int i4 = blockIdx.x * 256 + threadIdx.x; i4 < total4; i4 += gridDim.x * 256) {
        const int i = i4 << 2;
        const int ch = (i / N_) % C1;
        const float sc = g[ch] * istd[ch];
        const float sh = bt[ch] - mean[ch] * sc;
        float4 y = *(float4*)&Y[i];
        const float4 x = *(const float4*)&X[i];
        y.x = fmaxf(fmaf(y.x, sc, sh) + x.x, 0.f);
        y.y = fmaxf(fmaf(y.y, sc, sh) + x.y, 0.f);
        y.z = fmaxf(fmaf(y.z, sc, sh) + x.z, 0.f);
        y.w = fmaxf(fmaf(y.w, sc, sh) + x.w, 0.f);
        *(float4*)&Y[i] = y;
    }
}

extern "C" void kernel_launch(void* const* d_in, const int* in_sizes, int n_in,
                              void* d_out, int out_size, void* d_ws, size_t ws_size,
                              hipStream_t stream)
{
    const float* x  = (const float*)d_in[0];
    const float* W1 = (const float*)d_in[1];
    const float* g1 = (const float*)d_in[2];
    const float* b1 = (const float*)d_in[3];
    const float* Wq = (const float*)d_in[4];
    const float* bq = (const float*)d_in[5];
    const float* Wk = (const float*)d_in[6];
    const float* bk = (const float*)d_in[7];
    const float* Wv = (const float*)d_in[8];
    const float* bv = (const float*)d_in[9];
    const float* rh = (const float*)d_in[10];
    const float* rw = (const float*)d_in[11];
    const float* rd = (const float*)d_in[12];
    const float* g2 = (const float*)d_in[13];
    const float* b2 = (const float*)d_in[14];
    const float* W3 = (const float*)d_in[15];
    const float* g3 = (const float*)d_in[16];
    const float* b3 = (const float*)d_in[17];
    float* out = (float*)d_out;

    float* ws = (float*)d_ws;
    // region A (5,619,712 f32): xT, later QAt+KBt
    unsigned short* xT  = (unsigned short*)ws;
    unsigned short* QAt = (unsigned short*)ws;                 // 2,809,856 f32
    unsigned short* KBt = (unsigned short*)(ws + 2809856);     // 2,809,856 f32
    // region B (2,809,856 f32): Y1t f32, later Ot f32
    float* Y1t = ws + 5619712;
    float* Ot  = Y1t;
    // region C (1,404,928 f32): Y1t16, later Obt16
    unsigned short* Y1t16 = (unsigned short*)(ws + 8429568);
    unsigned short* Obt16 = Y1t16;
    // region D (1,404,928 f32): Vb16
    unsigned short* Vb16 = (unsigned short*)(ws + 9834496);
    // region E (360,448 f32): bf16 weights
    unsigned short* Wb = (unsigned short*)(ws + 11239424);
    unsigned short* W1b = Wb;
    unsigned short* Wqkb = Wb + 262144;   // [512][256] = Wq ; Wk stacked
    unsigned short* Wvb = Wb + 393216;
    unsigned short* W3b = Wb + 458752;
    // region F: stats
    float* st = ws + 11599872;
    float* sums1 = st;             // 512
    float* sums2 = st + 512;       // 512
    float* scsh1 = st + 1024;      // 512
    float* scsh2 = st + 1536;      // 512
    float* m3 = st + 2048;         // 1024
    float* i3 = st + 3072;         // 1024

    dim3 blk(256);

    prep<<<dim3(705), blk, 0, stream>>>(W1, Wq, Wk, Wv, W3, Wb, sums1);
    xt_kernel<<<dim3(43, 16, B_), blk, 0, stream>>>(x, xT);

    // conv1: D[n][o] f32 -> Y1t
    gemm_nt<<<dim3(22, 4, B_), blk, 0, stream>>>(xT, W1b, nullptr, nullptr, Y1t, nullptr,
        N_, 256, 1024, (long)N_ * 1024, 0, (long)N_ * 256, 256, 0);
    bn_stats_t<<<dim3(128), blk, 0, stream>>>(Y1t, sums1);
    bn_finalize_t<<<dim3(1), blk, 0, stream>>>(sums1, g1, b1, scsh1);
    bn_apply_t<<<dim3(1024), blk, 0, stream>>>(Y1t, scsh1, Y1t16);

    rel_fill<<<dim3((HEADS_ * 16 * N_ + 255) / 256), blk, 0, stream>>>(rh, rw, rd, QAt);

    // fused Q+K projection (NC=512), V projection
    gemm_nt<<<dim3(22, 8, B_), blk, 0, stream>>>(Y1t16, Wqkb, bq, bk, QAt, KBt,
        N_, 512, 256, (long)N_ * 256, 0, 0, 0, 1);
    gemm_nt<<<dim3(2, 43, B_), blk, 0, stream>>>(Wvb, Y1t16, bv, nullptr, Vb16, nullptr,
        256, N_, 256, 0, (long)N_ * 256, 0, 0, 3);

    // flash attention -> Ot [b][n][256] f32
    attn_mfma<<<dim3(688), blk, 0, stream>>>(QAt, KBt, Vb16, Ot);

    // BN2 + ReLU -> Obt16
    bn_stats_t<<<dim3(128), blk, 0, stream>>>(Ot, sums2);
    bn_finalize_t<<<dim3(1), blk, 0, stream>>>(sums2, g2, b2, scsh2);
    bn_apply_t<<<dim3(1024), blk, 0, stream>>>(Ot, scsh2, Obt16);

    // conv3: D[o][n] f32 -> out
    gemm_nt<<<dim3(8, 43, B_), blk, 0, stream>>>(W3b, Obt16, nullptr, nullptr, out, nullptr,
        1024, N_, 256, 0, (long)N_ * 256, (long)C1 * N_, N_, 0);
    bn_stats<<<dim3(C1), blk, 0, stream>>>(out, m3, i3, C1);
    bn_add_relu<<<dim3(2048), blk, 0, stream>>>(out, x, g3, b3, m3, i3);

    (void)in_sizes; (void)n_in; (void)out_size; (void)ws_size;
}